// Round 1
// baseline (1088.629 us; speedup 1.0000x reference)
//
#include <hip/hip_runtime.h>

#define EMB   1024
#define HEADS 16
#define HDIM  64
#define BATCH 2
#define SEQ   2048
#define MROWS (BATCH*SEQ)   // 4096

// ---------------------------------------------------------------------------
// Kernel 1: QKV projection.  Out[z][b][h][t][d] = sum_e X[b][t][e]*W_z[h][e][d]
// grid (MROWS/64, HEADS, 3), block 256.  64x64 C-tile, BK=16, 4x4 per thread.
// LDS A stored transposed [k][row] so compute reads are 2x ds_read_b128/16FMA.
// ---------------------------------------------------------------------------
__global__ __launch_bounds__(256)
void qkv_gemm(const float* __restrict__ X,
              const float* __restrict__ Wq,
              const float* __restrict__ Wk,
              const float* __restrict__ Wv,
              float* __restrict__ Qo, float* __restrict__ Ko,
              float* __restrict__ Vo)
{
    const int m0 = blockIdx.x * 64;
    const int h  = blockIdx.y;
    const int z  = blockIdx.z;
    const float* W  = (z == 0) ? Wq : (z == 1) ? Wk : Wv;
    float*      Out = (z == 0) ? Qo : (z == 1) ? Ko : Vo;

    __shared__ float AsT[16][68];   // [k][row], padded: conflict-free scatter
    __shared__ float Bs [16][64];   // [k][d]  (W is already k-major)

    const int t  = threadIdx.x;
    const int tx = t & 15, ty = t >> 4;

    const int arow = t >> 2;         // 0..63
    const int akk  = (t & 3) * 4;    // 0,4,8,12
    const int brow = t >> 4;         // 0..15
    const int bcc  = (t & 15) * 4;   // 0..60

    float acc[4][4] = {};

    for (int k0 = 0; k0 < EMB; k0 += 16) {
        float4 a4 = *(const float4*)(X + (size_t)(m0 + arow) * EMB + k0 + akk);
        float4 b4 = *(const float4*)(W + (size_t)h * EMB * HDIM
                                       + (size_t)(k0 + brow) * HDIM + bcc);
        AsT[akk + 0][arow] = a4.x;
        AsT[akk + 1][arow] = a4.y;
        AsT[akk + 2][arow] = a4.z;
        AsT[akk + 3][arow] = a4.w;
        *(float4*)&Bs[brow][bcc] = b4;
        __syncthreads();
#pragma unroll
        for (int k = 0; k < 16; ++k) {
            float4 av = *(const float4*)&AsT[k][ty * 4];
            float4 bv = *(const float4*)&Bs [k][tx * 4];
            float a[4] = {av.x, av.y, av.z, av.w};
            float b[4] = {bv.x, bv.y, bv.z, bv.w};
#pragma unroll
            for (int i = 0; i < 4; ++i)
#pragma unroll
                for (int j = 0; j < 4; ++j) acc[i][j] += a[i] * b[j];
        }
        __syncthreads();
    }
#pragma unroll
    for (int i = 0; i < 4; ++i) {
        int m  = m0 + ty * 4 + i;
        int bb = m >> 11, tt = m & (SEQ - 1);
        float4 o = make_float4(acc[i][0], acc[i][1], acc[i][2], acc[i][3]);
        *(float4*)(Out + ((size_t)(bb * HEADS + h) * SEQ + tt) * HDIM + tx * 4) = o;
    }
}

// ---------------------------------------------------------------------------
// Kernel 2: flash-style attention per (b,h).  grid (SEQ/64, BATCH*HEADS),
// block 256.  64 Q-rows per block, iterate 32 K/V tiles of 64 rows.
// All-fp32 (precision: logits sigma~1024, near-argmax softmax).
// KV buffer shared between K^T ([d][s]) and V ([s][d]) phases.
// ---------------------------------------------------------------------------
__global__ __launch_bounds__(256)
void attn(const float* __restrict__ Q, const float* __restrict__ K,
          const float* __restrict__ V, float* __restrict__ C)
{
    const int qt0 = blockIdx.x * 64;
    const int bh  = blockIdx.y;                 // b*HEADS + h
    const float* Qb = Q + (size_t)bh * SEQ * HDIM;
    const float* Kb = K + (size_t)bh * SEQ * HDIM;
    const float* Vb = V + (size_t)bh * SEQ * HDIM;

    __shared__ float Qs[64][68];   // [qrow][d]
    __shared__ float KV[64][68];   // phase 1: K^T [d][s]; phase 2: V [s][d]
    __shared__ float Ps[64][68];   // [qrow][s]

    const int t  = threadIdx.x;
    const int tx = t & 15, ty = t >> 4;

#pragma unroll
    for (int i = 0; i < 4; ++i) {
        int idx = t + i * 256;                  // 0..1023 float4 slots
        int row = idx >> 4, c4 = (idx & 15) * 4;
        float4 q4 = *(const float4*)(Qb + (size_t)(qt0 + row) * HDIM + c4);
        Qs[row][c4 + 0] = q4.x; Qs[row][c4 + 1] = q4.y;
        Qs[row][c4 + 2] = q4.z; Qs[row][c4 + 3] = q4.w;
    }

    float m_i[4], l_i[4], O[4][4];
#pragma unroll
    for (int i = 0; i < 4; ++i) {
        m_i[i] = -1e30f; l_i[i] = 0.f;
#pragma unroll
        for (int j = 0; j < 4; ++j) O[i][j] = 0.f;
    }

    for (int s0 = 0; s0 < SEQ; s0 += 64) {
        // prefetch K and V tiles into registers (before barrier)
        float4 kreg[4], vreg[4];
#pragma unroll
        for (int i = 0; i < 4; ++i) {
            int idx = t + i * 256;
            int row = idx >> 4, c4 = (idx & 15) * 4;
            kreg[i] = *(const float4*)(Kb + (size_t)(s0 + row) * HDIM + c4);
            vreg[i] = *(const float4*)(Vb + (size_t)(s0 + row) * HDIM + c4);
        }
        __syncthreads();                        // (A) prev PV done with KV
#pragma unroll
        for (int i = 0; i < 4; ++i) {           // scatter K^T: KV[d][s]
            int idx = t + i * 256;
            int row = idx >> 4, c4 = (idx & 15) * 4;
            KV[c4 + 0][row] = kreg[i].x; KV[c4 + 1][row] = kreg[i].y;
            KV[c4 + 2][row] = kreg[i].z; KV[c4 + 3][row] = kreg[i].w;
        }
        __syncthreads();                        // (B) K^T visible

        // S = (Q K^T) * scale, 4x4 per thread
        float S[4][4] = {};
#pragma unroll
        for (int d4 = 0; d4 < 16; ++d4) {
            float qa[4][4], ka[4][4];
#pragma unroll
            for (int i = 0; i < 4; ++i) {
                float4 v = *(const float4*)&Qs[ty * 4 + i][d4 * 4];
                qa[i][0] = v.x; qa[i][1] = v.y; qa[i][2] = v.z; qa[i][3] = v.w;
            }
#pragma unroll
            for (int dd = 0; dd < 4; ++dd) {
                float4 v = *(const float4*)&KV[d4 * 4 + dd][tx * 4];
                ka[0][dd] = v.x; ka[1][dd] = v.y; ka[2][dd] = v.z; ka[3][dd] = v.w;
            }
#pragma unroll
            for (int i = 0; i < 4; ++i)
#pragma unroll
                for (int j = 0; j < 4; ++j)
#pragma unroll
                    for (int dd = 0; dd < 4; ++dd)
                        S[i][j] += qa[i][dd] * ka[j][dd];
        }
#pragma unroll
        for (int i = 0; i < 4; ++i)
#pragma unroll
            for (int j = 0; j < 4; ++j) S[i][j] *= 0.125f;

        // online softmax update
        float rm[4], alpha[4], P[4][4], rs[4];
#pragma unroll
        for (int i = 0; i < 4; ++i)
            rm[i] = fmaxf(fmaxf(S[i][0], S[i][1]), fmaxf(S[i][2], S[i][3]));
#pragma unroll
        for (int mask = 1; mask < 16; mask <<= 1)
#pragma unroll
            for (int i = 0; i < 4; ++i)
                rm[i] = fmaxf(rm[i], __shfl_xor(rm[i], mask, 64));
#pragma unroll
        for (int i = 0; i < 4; ++i) {
            float mn = fmaxf(m_i[i], rm[i]);
            alpha[i] = __expf(m_i[i] - mn);
            m_i[i]   = mn;
            rs[i]    = 0.f;
        }
#pragma unroll
        for (int i = 0; i < 4; ++i)
#pragma unroll
            for (int j = 0; j < 4; ++j) {
                P[i][j] = __expf(S[i][j] - m_i[i]);
                rs[i]  += P[i][j];
            }
#pragma unroll
        for (int mask = 1; mask < 16; mask <<= 1)
#pragma unroll
            for (int i = 0; i < 4; ++i)
                rs[i] += __shfl_xor(rs[i], mask, 64);
#pragma unroll
        for (int i = 0; i < 4; ++i) {
            l_i[i] = l_i[i] * alpha[i] + rs[i];
#pragma unroll
            for (int j = 0; j < 4; ++j) O[i][j] *= alpha[i];
            *(float4*)&Ps[ty * 4 + i][tx * 4] =
                make_float4(P[i][0], P[i][1], P[i][2], P[i][3]);
        }
        __syncthreads();                        // (C) KV(K) reads done, Ps out
#pragma unroll
        for (int i = 0; i < 4; ++i) {           // V into KV as [s][d]
            int idx = t + i * 256;
            int row = idx >> 4, c4 = (idx & 15) * 4;
            *(float4*)&KV[row][c4] = vreg[i];
        }
        __syncthreads();                        // (D) V + Ps visible

        // O += P @ V
#pragma unroll
        for (int s4 = 0; s4 < 16; ++s4) {
            float pa[4][4], va[4][4];
#pragma unroll
            for (int i = 0; i < 4; ++i) {
                float4 v = *(const float4*)&Ps[ty * 4 + i][s4 * 4];
                pa[i][0] = v.x; pa[i][1] = v.y; pa[i][2] = v.z; pa[i][3] = v.w;
            }
#pragma unroll
            for (int ss = 0; ss < 4; ++ss) {
                float4 v = *(const float4*)&KV[s4 * 4 + ss][tx * 4];
                va[ss][0] = v.x; va[ss][1] = v.y; va[ss][2] = v.z; va[ss][3] = v.w;
            }
#pragma unroll
            for (int i = 0; i < 4; ++i)
#pragma unroll
                for (int j = 0; j < 4; ++j)
#pragma unroll
                    for (int ss = 0; ss < 4; ++ss)
                        O[i][j] += pa[i][ss] * va[ss][j];
        }
    }

    // normalize and store to combined [b][t][h*64+d]
    const int b = bh >> 4, h = bh & 15;
#pragma unroll
    for (int i = 0; i < 4; ++i) {
        float inv = 1.f / l_i[i];
        int   tt  = qt0 + ty * 4 + i;
        float4 o  = make_float4(O[i][0] * inv, O[i][1] * inv,
                                O[i][2] * inv, O[i][3] * inv);
        *(float4*)(C + ((size_t)b * SEQ + tt) * EMB + h * HDIM + tx * 4) = o;
    }
}

// ---------------------------------------------------------------------------
// Kernel 3: Y = X + C @ Wo^T.  grid (MROWS/64, EMB/64), block 256.
// Both operands K-contiguous; LDS tiles stored [k][row] for b128 reads.
// ---------------------------------------------------------------------------
__global__ __launch_bounds__(256)
void oproj(const float* __restrict__ Cm, const float* __restrict__ Wo,
           const float* __restrict__ X, float* __restrict__ Y)
{
    const int m0 = blockIdx.x * 64, n0 = blockIdx.y * 64;
    __shared__ float AsT[16][68];   // [k][m-row]
    __shared__ float BsT[16][68];   // [k][n-row]

    const int t  = threadIdx.x;
    const int tx = t & 15, ty = t >> 4;
    const int row = t >> 2;          // 0..63
    const int kk  = (t & 3) * 4;     // 0,4,8,12

    float acc[4][4] = {};

    for (int k0 = 0; k0 < EMB; k0 += 16) {
        float4 a4 = *(const float4*)(Cm + (size_t)(m0 + row) * EMB + k0 + kk);
        float4 b4 = *(const float4*)(Wo + (size_t)(n0 + row) * EMB + k0 + kk);
        AsT[kk + 0][row] = a4.x; AsT[kk + 1][row] = a4.y;
        AsT[kk + 2][row] = a4.z; AsT[kk + 3][row] = a4.w;
        BsT[kk + 0][row] = b4.x; BsT[kk + 1][row] = b4.y;
        BsT[kk + 2][row] = b4.z; BsT[kk + 3][row] = b4.w;
        __syncthreads();
#pragma unroll
        for (int k = 0; k < 16; ++k) {
            float4 av = *(const float4*)&AsT[k][ty * 4];
            float4 bv = *(const float4*)&BsT[k][tx * 4];
            float a[4] = {av.x, av.y, av.z, av.w};
            float b[4] = {bv.x, bv.y, bv.z, bv.w};
#pragma unroll
            for (int i = 0; i < 4; ++i)
#pragma unroll
                for (int j = 0; j < 4; ++j) acc[i][j] += a[i] * b[j];
        }
        __syncthreads();
    }
#pragma unroll
    for (int i = 0; i < 4; ++i) {
        int m = m0 + ty * 4 + i;
        float4 x4 = *(const float4*)(X + (size_t)m * EMB + n0 + tx * 4);
        float4 o  = make_float4(acc[i][0] + x4.x, acc[i][1] + x4.y,
                                acc[i][2] + x4.z, acc[i][3] + x4.w);
        *(float4*)(Y + (size_t)m * EMB + n0 + tx * 4) = o;
    }
}

// ---------------------------------------------------------------------------
extern "C" void kernel_launch(void* const* d_in, const int* in_sizes, int n_in,
                              void* d_out, int out_size, void* d_ws,
                              size_t ws_size, hipStream_t stream)
{
    const float* x  = (const float*)d_in[0];
    const float* Wq = (const float*)d_in[1];
    const float* Wk = (const float*)d_in[2];
    const float* Wv = (const float*)d_in[3];
    const float* Wo = (const float*)d_in[4];
    float* Y = (float*)d_out;

    const size_t per = (size_t)BATCH * HEADS * SEQ * HDIM;   // 4,194,304
    float* Q = (float*)d_ws;
    float* K = Q + per;
    float* V = K + per;
    float* C = V + per;   // [B][T][E], 4,194,304 floats; total ws = 64 MiB

    qkv_gemm<<<dim3(MROWS / 64, HEADS, 3), 256, 0, stream>>>(x, Wq, Wk, Wv,
                                                             Q, K, V);
    attn<<<dim3(SEQ / 64, BATCH * HEADS), 256, 0, stream>>>(Q, K, V, C);
    oproj<<<dim3(MROWS / 64, EMB / 64), 256, 0, stream>>>(C, Wo, x, Y);
}

// Round 2
// 603.032 us; speedup vs baseline: 1.8053x; 1.8053x over previous
//
#include <hip/hip_runtime.h>

#define EMB   1024
#define HEADS 16
#define HDIM  64
#define BATCH 2
#define SEQ   2048
#define MROWS (BATCH*SEQ)   // 4096

typedef __attribute__((ext_vector_type(8))) short bf16x8;   // 8 bf16 (4 VGPRs)
typedef __attribute__((ext_vector_type(4))) float f32x4;    // MFMA C/D
typedef unsigned short u16;

__device__ __forceinline__ u16 f2bf(float f) {              // round-to-nearest-even
    unsigned u = __float_as_uint(f);
    u += 0x7fffu + ((u >> 16) & 1u);
    return (u16)(u >> 16);
}
__device__ __forceinline__ float bf2f(u16 h) {
    return __uint_as_float((unsigned)h << 16);
}

// ---------------------------------------------------------------------------
// Wo -> bf16 elementwise.  grid 1024, block 256 (1M elems, 4/thread).
// ---------------------------------------------------------------------------
__global__ __launch_bounds__(256)
void conv_bf16(const float* __restrict__ src, u16* __restrict__ dst)
{
    int i = (blockIdx.x * 256 + threadIdx.x) * 4;
    float4 v = *(const float4*)(src + i);
    ushort4 o;
    o.x = f2bf(v.x); o.y = f2bf(v.y); o.z = f2bf(v.z); o.w = f2bf(v.w);
    *(ushort4*)(dst + i) = o;
}

// ---------------------------------------------------------------------------
// Kernel 1: QKV projection, fp32 core (unchanged from R1 — correct & VALU-bound;
// MFMA conversion is next round).  New epilogue:
//   z=0 -> Qh/Ql bf16 hi+lo [bh][t][d]     (split for 3-pass QK^T)
//   z=1 -> Kh/Kl bf16 hi+lo [bh][t][d]
//   z=2 -> Vt   bf16 TRANSPOSED [bh][d][t] (contiguous PV B-operand reads)
// ---------------------------------------------------------------------------
__global__ __launch_bounds__(256)
void qkv_gemm(const float* __restrict__ X,
              const float* __restrict__ Wq,
              const float* __restrict__ Wk,
              const float* __restrict__ Wv,
              u16* __restrict__ Qh, u16* __restrict__ Ql,
              u16* __restrict__ Kh, u16* __restrict__ Kl,
              u16* __restrict__ Vt)
{
    const int m0 = blockIdx.x * 64;
    const int h  = blockIdx.y;
    const int z  = blockIdx.z;
    const float* W = (z == 0) ? Wq : (z == 1) ? Wk : Wv;

    __shared__ float AsT[16][68];
    __shared__ float Bs [16][64];

    const int t  = threadIdx.x;
    const int tx = t & 15, ty = t >> 4;
    const int arow = t >> 2;
    const int akk  = (t & 3) * 4;
    const int brow = t >> 4;
    const int bcc  = (t & 15) * 4;

    float acc[4][4] = {};

    for (int k0 = 0; k0 < EMB; k0 += 16) {
        float4 a4 = *(const float4*)(X + (size_t)(m0 + arow) * EMB + k0 + akk);
        float4 b4 = *(const float4*)(W + (size_t)h * EMB * HDIM
                                       + (size_t)(k0 + brow) * HDIM + bcc);
        AsT[akk + 0][arow] = a4.x; AsT[akk + 1][arow] = a4.y;
        AsT[akk + 2][arow] = a4.z; AsT[akk + 3][arow] = a4.w;
        *(float4*)&Bs[brow][bcc] = b4;
        __syncthreads();
#pragma unroll
        for (int k = 0; k < 16; ++k) {
            float4 av = *(const float4*)&AsT[k][ty * 4];
            float4 bv = *(const float4*)&Bs [k][tx * 4];
            float a[4] = {av.x, av.y, av.z, av.w};
            float b[4] = {bv.x, bv.y, bv.z, bv.w};
#pragma unroll
            for (int i = 0; i < 4; ++i)
#pragma unroll
                for (int j = 0; j < 4; ++j) acc[i][j] += a[i] * b[j];
        }
        __syncthreads();
    }

    if (z == 2) {
        // Vt[bh][d][t], pack 4 consecutive t (rows i=0..3) per store
        int m  = m0 + ty * 4;
        int bb = m >> 11, tt = m & (SEQ - 1);
#pragma unroll
        for (int j = 0; j < 4; ++j) {
            int d = tx * 4 + j;
            ushort4 o;
            o.x = f2bf(acc[0][j]); o.y = f2bf(acc[1][j]);
            o.z = f2bf(acc[2][j]); o.w = f2bf(acc[3][j]);
            *(ushort4*)(Vt + ((size_t)(bb * HEADS + h) * HDIM + d) * SEQ + tt) = o;
        }
    } else {
        u16* Oh = (z == 0) ? Qh : Kh;
        u16* Ol = (z == 0) ? Ql : Kl;
#pragma unroll
        for (int i = 0; i < 4; ++i) {
            int m  = m0 + ty * 4 + i;
            int bb = m >> 11, tt = m & (SEQ - 1);
            ushort4 hi4, lo4;
            u16 hv; float v, lf;
            v = acc[i][0]; hv = f2bf(v); hi4.x = hv; lf = v - bf2f(hv); lo4.x = f2bf(lf);
            v = acc[i][1]; hv = f2bf(v); hi4.y = hv; lf = v - bf2f(hv); lo4.y = f2bf(lf);
            v = acc[i][2]; hv = f2bf(v); hi4.z = hv; lf = v - bf2f(hv); lo4.z = f2bf(lf);
            v = acc[i][3]; hv = f2bf(v); hi4.w = hv; lf = v - bf2f(hv); lo4.w = f2bf(lf);
            size_t base = ((size_t)(bb * HEADS + h) * SEQ + tt) * HDIM + tx * 4;
            *(ushort4*)(Oh + base) = hi4;
            *(ushort4*)(Ol + base) = lo4;
        }
    }
}

// ---------------------------------------------------------------------------
// Kernel 2: flash attention, MFMA 16x16x32 bf16.
// grid (SEQ/64, BATCH*HEADS), block 256 = 4 waves; wave owns 16 q-rows x 64 d.
// QK^T: 3-pass split-bf16 (Qh*Kh + Qh*Kl + Ql*Kh) -> fp32 logits (~16-bit acc).
// A-frag:  A[m=lane&15][k=quad*8+j];  B-frag: B[k=quad*8+j][n=lane&15].
// C/D:     col=lane&15, row=quad*4+reg   (m89-verified layouts).
// P: C-layout -> LDS -> A-layout round-trip (per-wave rows only, no barrier).
// ---------------------------------------------------------------------------
__global__ __launch_bounds__(256)
void attn_mfma(const u16* __restrict__ Qh, const u16* __restrict__ Ql,
               const u16* __restrict__ Kh, const u16* __restrict__ Kl,
               const u16* __restrict__ Vt, u16* __restrict__ Cb)
{
    const int qt0  = blockIdx.x * 64;
    const int bh   = blockIdx.y;
    const int t    = threadIdx.x;
    const int wave = t >> 6;
    const int lane = t & 63;
    const int l16  = lane & 15;
    const int quad = lane >> 4;

    __shared__ u16 Ksh[64][72];   // K hi  [s][d]  (stride 72: 2-way = free)
    __shared__ u16 Ksl[64][72];   // K lo  [s][d]
    __shared__ u16 Vs [64][72];   // V^T   [d][s]
    __shared__ u16 Ps [64][72];   // P     [q][s]

    const size_t bh_off = (size_t)bh * SEQ * HDIM;
    const u16* Qhb = Qh + bh_off;
    const u16* Qlb = Ql + bh_off;
    const u16* Khb = Kh + bh_off;
    const u16* Klb = Kl + bh_off;
    const u16* Vtb = Vt + bh_off;   // [64][SEQ]

    // Q fragments: registers for the whole kernel (reused over 32 K-tiles)
    bf16x8 aQh[2], aQl[2];
    {
        const int qrow = qt0 + wave * 16 + l16;
        const u16* bH = Qhb + (size_t)qrow * HDIM + quad * 8;
        const u16* bL = Qlb + (size_t)qrow * HDIM + quad * 8;
        aQh[0] = *(const bf16x8*)(bH);
        aQh[1] = *(const bf16x8*)(bH + 32);
        aQl[0] = *(const bf16x8*)(bL);
        aQl[1] = *(const bf16x8*)(bL + 32);
    }

    f32x4 accO[4];
    float m_i[4], l_i[4];
#pragma unroll
    for (int j = 0; j < 4; ++j) { accO[j] = (f32x4){0.f, 0.f, 0.f, 0.f}; }
#pragma unroll
    for (int r = 0; r < 4; ++r) { m_i[r] = -1e30f; l_i[r] = 0.f; }

    const int ch0 = t, ch1 = t + 256;          // 512 x 16B chunks per tile
    const int r0 = ch0 >> 3, c0 = (ch0 & 7) * 8;
    const int r1 = ch1 >> 3, c1 = (ch1 & 7) * 8;

    for (int s0 = 0; s0 < SEQ; s0 += 64) {
        // prefetch K hi/lo + V tiles to registers (overlaps with barrier wait)
        bf16x8 kh0 = *(const bf16x8*)(Khb + (size_t)(s0 + r0) * HDIM + c0);
        bf16x8 kh1 = *(const bf16x8*)(Khb + (size_t)(s0 + r1) * HDIM + c1);
        bf16x8 kl0 = *(const bf16x8*)(Klb + (size_t)(s0 + r0) * HDIM + c0);
        bf16x8 kl1 = *(const bf16x8*)(Klb + (size_t)(s0 + r1) * HDIM + c1);
        bf16x8 vv0 = *(const bf16x8*)(Vtb + (size_t)r0 * SEQ + s0 + c0);
        bf16x8 vv1 = *(const bf16x8*)(Vtb + (size_t)r1 * SEQ + s0 + c1);
        __syncthreads();                       // prev iteration done with LDS
        *(bf16x8*)&Ksh[r0][c0] = kh0;  *(bf16x8*)&Ksh[r1][c1] = kh1;
        *(bf16x8*)&Ksl[r0][c0] = kl0;  *(bf16x8*)&Ksl[r1][c1] = kl1;
        *(bf16x8*)&Vs [r0][c0] = vv0;  *(bf16x8*)&Vs [r1][c1] = vv1;
        __syncthreads();                       // tiles visible

        // ---- S = Q K^T (3-pass split) ----
        f32x4 accS[4];
#pragma unroll
        for (int j = 0; j < 4; ++j) accS[j] = (f32x4){0.f, 0.f, 0.f, 0.f};
#pragma unroll
        for (int c = 0; c < 2; ++c) {
#pragma unroll
            for (int j = 0; j < 4; ++j) {
                bf16x8 bh_ = *(const bf16x8*)&Ksh[16 * j + l16][c * 32 + quad * 8];
                bf16x8 bl_ = *(const bf16x8*)&Ksl[16 * j + l16][c * 32 + quad * 8];
                accS[j] = __builtin_amdgcn_mfma_f32_16x16x32_bf16(aQh[c], bh_, accS[j], 0, 0, 0);
                accS[j] = __builtin_amdgcn_mfma_f32_16x16x32_bf16(aQh[c], bl_, accS[j], 0, 0, 0);
                accS[j] = __builtin_amdgcn_mfma_f32_16x16x32_bf16(aQl[c], bh_, accS[j], 0, 0, 0);
            }
        }
#pragma unroll
        for (int j = 0; j < 4; ++j) accS[j] *= 0.125f;   // 1/sqrt(64)

        // ---- online softmax (rows live across 16-lane groups) ----
        float P[4][4];
#pragma unroll
        for (int r = 0; r < 4; ++r) {
            float v = fmaxf(fmaxf(accS[0][r], accS[1][r]),
                            fmaxf(accS[2][r], accS[3][r]));
#pragma unroll
            for (int mk = 1; mk < 16; mk <<= 1) v = fmaxf(v, __shfl_xor(v, mk, 64));
            float mn   = fmaxf(m_i[r], v);
            float alph = __expf(m_i[r] - mn);
            m_i[r] = mn;
            float s = 0.f;
#pragma unroll
            for (int j = 0; j < 4; ++j) { P[j][r] = __expf(accS[j][r] - mn); s += P[j][r]; }
#pragma unroll
            for (int mk = 1; mk < 16; mk <<= 1) s += __shfl_xor(s, mk, 64);
            l_i[r] = l_i[r] * alph + s;
#pragma unroll
            for (int j = 0; j < 4; ++j) accO[j][r] *= alph;
        }

        // P: C-layout -> LDS (wave's own 16 rows; same-wave RAW, no barrier)
#pragma unroll
        for (int r = 0; r < 4; ++r)
#pragma unroll
            for (int j = 0; j < 4; ++j)
                Ps[wave * 16 + quad * 4 + r][16 * j + l16] = f2bf(P[j][r]);

        // ---- O += P V ----
#pragma unroll
        for (int c = 0; c < 2; ++c) {
            bf16x8 aP = *(const bf16x8*)&Ps[wave * 16 + l16][c * 32 + quad * 8];
#pragma unroll
            for (int j = 0; j < 4; ++j) {
                bf16x8 bV = *(const bf16x8*)&Vs[16 * j + l16][c * 32 + quad * 8];
                accO[j] = __builtin_amdgcn_mfma_f32_16x16x32_bf16(aP, bV, accO[j], 0, 0, 0);
            }
        }
    }

    // epilogue: normalize, write C bf16 [b][t][h*64+d]
    const int b = bh >> 4, h = bh & 15;
#pragma unroll
    for (int r = 0; r < 4; ++r) {
        float inv = 1.f / l_i[r];
        int  row  = qt0 + wave * 16 + quad * 4 + r;
#pragma unroll
        for (int j = 0; j < 4; ++j) {
            int col = h * HDIM + 16 * j + l16;
            Cb[((size_t)b * SEQ + row) * EMB + col] = f2bf(accO[j][r] * inv);
        }
    }
}

// ---------------------------------------------------------------------------
// Kernel 3: Y = X + C @ Wo^T, bf16 MFMA.  grid (MROWS/64, EMB/64), 4 waves.
// Wo is [out][in] = B^T form already: b-frag reads are contiguous.
// ---------------------------------------------------------------------------
__global__ __launch_bounds__(256)
void oproj_mfma(const u16* __restrict__ Cb, const u16* __restrict__ Woh,
                const float* __restrict__ X, float* __restrict__ Y)
{
    const int m0 = blockIdx.x * 64, n0 = blockIdx.y * 64;
    const int t    = threadIdx.x;
    const int wave = t >> 6;
    const int lane = t & 63;
    const int l16  = lane & 15;
    const int quad = lane >> 4;

    __shared__ u16 As[64][72];   // C rows  [m][k]
    __shared__ u16 Bs[64][72];   // Wo rows [n][k]

    const int ch0 = t, ch1 = t + 256;
    const int r0 = ch0 >> 3, c0 = (ch0 & 7) * 8;
    const int r1 = ch1 >> 3, c1 = (ch1 & 7) * 8;

    f32x4 acc[4];
#pragma unroll
    for (int j = 0; j < 4; ++j) acc[j] = (f32x4){0.f, 0.f, 0.f, 0.f};

    for (int k0 = 0; k0 < EMB; k0 += 64) {
        bf16x8 a0 = *(const bf16x8*)(Cb  + (size_t)(m0 + r0) * EMB + k0 + c0);
        bf16x8 a1 = *(const bf16x8*)(Cb  + (size_t)(m0 + r1) * EMB + k0 + c1);
        bf16x8 b0 = *(const bf16x8*)(Woh + (size_t)(n0 + r0) * EMB + k0 + c0);
        bf16x8 b1 = *(const bf16x8*)(Woh + (size_t)(n0 + r1) * EMB + k0 + c1);
        __syncthreads();
        *(bf16x8*)&As[r0][c0] = a0;  *(bf16x8*)&As[r1][c1] = a1;
        *(bf16x8*)&Bs[r0][c0] = b0;  *(bf16x8*)&Bs[r1][c1] = b1;
        __syncthreads();
#pragma unroll
        for (int c = 0; c < 2; ++c) {
            bf16x8 aA = *(const bf16x8*)&As[wave * 16 + l16][c * 32 + quad * 8];
#pragma unroll
            for (int j = 0; j < 4; ++j) {
                bf16x8 bB = *(const bf16x8*)&Bs[16 * j + l16][c * 32 + quad * 8];
                acc[j] = __builtin_amdgcn_mfma_f32_16x16x32_bf16(aA, bB, acc[j], 0, 0, 0);
            }
        }
    }

    // epilogue: + residual, fp32 out
#pragma unroll
    for (int r = 0; r < 4; ++r) {
        int m = m0 + wave * 16 + quad * 4 + r;
#pragma unroll
        for (int j = 0; j < 4; ++j) {
            int n = n0 + 16 * j + l16;
            Y[(size_t)m * EMB + n] = acc[j][r] + X[(size_t)m * EMB + n];
        }
    }
}

// ---------------------------------------------------------------------------
extern "C" void kernel_launch(void* const* d_in, const int* in_sizes, int n_in,
                              void* d_out, int out_size, void* d_ws,
                              size_t ws_size, hipStream_t stream)
{
    const float* x  = (const float*)d_in[0];
    const float* Wq = (const float*)d_in[1];
    const float* Wk = (const float*)d_in[2];
    const float* Wv = (const float*)d_in[3];
    const float* Wo = (const float*)d_in[4];
    float* Y = (float*)d_out;

    const size_t NPER = (size_t)BATCH * HEADS * SEQ * HDIM;   // 4,194,304
    u16* Qh  = (u16*)d_ws;        // layout: 6*NPER u16 + 1M u16 = 50 MiB total
    u16* Ql  = Qh + NPER;
    u16* Kh  = Ql + NPER;
    u16* Kl  = Kh + NPER;
    u16* Vt  = Kl + NPER;
    u16* Cb  = Vt + NPER;
    u16* Woh = Cb + NPER;

    conv_bf16<<<dim3(EMB * EMB / 1024), 256, 0, stream>>>(Wo, Woh);
    qkv_gemm<<<dim3(MROWS / 64, HEADS, 3), 256, 0, stream>>>(x, Wq, Wk, Wv,
                                                             Qh, Ql, Kh, Kl, Vt);
    attn_mfma<<<dim3(SEQ / 64, BATCH * HEADS), 256, 0, stream>>>(Qh, Ql, Kh, Kl,
                                                                 Vt, Cb);
    oproj_mfma<<<dim3(MROWS / 64, EMB / 64), 256, 0, stream>>>(Cb, Woh, x, Y);
}

// Round 3
// 391.191 us; speedup vs baseline: 2.7829x; 1.5415x over previous
//
#include <hip/hip_runtime.h>

#define EMB   1024
#define HEADS 16
#define HDIM  64
#define BATCH 2
#define SEQ   2048
#define MROWS (BATCH*SEQ)   // 4096
#define STR   40            // LDS k-stride in u16: 80 B = 5*16 (b128-aligned), 2-way banks

typedef __attribute__((ext_vector_type(8))) short bf16x8;   // 8 bf16 (4 VGPRs)
typedef __attribute__((ext_vector_type(4))) float f32x4;    // MFMA C/D
typedef unsigned short u16;

__device__ __forceinline__ u16 f2bf(float f) {              // round-to-nearest-even
    unsigned u = __float_as_uint(f);
    u += 0x7fffu + ((u >> 16) & 1u);
    return (u16)(u >> 16);
}
__device__ __forceinline__ float bf2f(u16 h) {
    return __uint_as_float((unsigned)h << 16);
}

// ---------------------------------------------------------------------------
// X -> Xh/Xl bf16 split.  4M elems, 8/thread -> 2048 blocks.
// ---------------------------------------------------------------------------
__global__ __launch_bounds__(256)
void xsplit(const float* __restrict__ X, u16* __restrict__ Xh,
            u16* __restrict__ Xl)
{
    int i = (blockIdx.x * 256 + threadIdx.x) * 8;
#pragma unroll
    for (int half = 0; half < 2; ++half) {
        float4 v = *(const float4*)(X + i + half * 4);
        ushort4 hi, lo;
        hi.x = f2bf(v.x); lo.x = f2bf(v.x - bf2f(hi.x));
        hi.y = f2bf(v.y); lo.y = f2bf(v.y - bf2f(hi.y));
        hi.z = f2bf(v.z); lo.z = f2bf(v.z - bf2f(hi.z));
        hi.w = f2bf(v.w); lo.w = f2bf(v.w - bf2f(hi.w));
        *(ushort4*)(Xh + i + half * 4) = hi;
        *(ushort4*)(Xl + i + half * 4) = lo;
    }
}

// ---------------------------------------------------------------------------
// Wq/Wk [16][1024][64] fp32 -> transposed hi/lo bf16 [h*64+d][e] (N-major,
// k-contiguous).  Lane d = coalesced loads; each lane's 8 e-values form its
// own contiguous output row chunk.  grid (32, 16, 2).
// ---------------------------------------------------------------------------
__global__ __launch_bounds__(256)
void wtrans(const float* __restrict__ Wq, const float* __restrict__ Wk,
            u16* __restrict__ Qth, u16* __restrict__ Qtl,
            u16* __restrict__ Kth, u16* __restrict__ Ktl)
{
    const float* W  = blockIdx.z ? Wk  : Wq;
    u16* Oh         = blockIdx.z ? Kth : Qth;
    u16* Ol         = blockIdx.z ? Ktl : Qtl;
    const int h  = blockIdx.y;
    const int d  = threadIdx.x & 63;
    const int e0 = (blockIdx.x * 4 + (threadIdx.x >> 6)) * 8;

    const float* src = W + ((size_t)h * EMB + e0) * HDIM + d;
    ushort4 h0, h1, l0, l1;
    float v; u16 hv;
    v = src[0 * 64]; hv = f2bf(v); h0.x = hv; l0.x = f2bf(v - bf2f(hv));
    v = src[1 * 64]; hv = f2bf(v); h0.y = hv; l0.y = f2bf(v - bf2f(hv));
    v = src[2 * 64]; hv = f2bf(v); h0.z = hv; l0.z = f2bf(v - bf2f(hv));
    v = src[3 * 64]; hv = f2bf(v); h0.w = hv; l0.w = f2bf(v - bf2f(hv));
    v = src[4 * 64]; hv = f2bf(v); h1.x = hv; l1.x = f2bf(v - bf2f(hv));
    v = src[5 * 64]; hv = f2bf(v); h1.y = hv; l1.y = f2bf(v - bf2f(hv));
    v = src[6 * 64]; hv = f2bf(v); h1.z = hv; l1.z = f2bf(v - bf2f(hv));
    v = src[7 * 64]; hv = f2bf(v); h1.w = hv; l1.w = f2bf(v - bf2f(hv));

    size_t obase = ((size_t)h * HDIM + d) * EMB + e0;
    *(ushort4*)(Oh + obase)     = h0;
    *(ushort4*)(Oh + obase + 4) = h1;
    *(ushort4*)(Ol + obase)     = l0;
    *(ushort4*)(Ol + obase + 4) = l1;
}

// ---------------------------------------------------------------------------
// Wo -> bf16 elementwise.
// ---------------------------------------------------------------------------
__global__ __launch_bounds__(256)
void conv_bf16(const float* __restrict__ src, u16* __restrict__ dst)
{
    int i = (blockIdx.x * 256 + threadIdx.x) * 4;
    float4 v = *(const float4*)(src + i);
    ushort4 o;
    o.x = f2bf(v.x); o.y = f2bf(v.y); o.z = f2bf(v.z); o.w = f2bf(v.w);
    *(ushort4*)(dst + i) = o;
}

// ---------------------------------------------------------------------------
// Kernel 1: QKV projection, MFMA 16x16x32 bf16.
// grid (32 m-tiles, 8 n-tiles, 3 z), block 256 = 4 waves (2x2), 128x128 tile,
// BK=32.  z=0/1 (Q,K): 3-pass split-bf16 (Ah*Bh + Ah*Bl + Al*Bh), epilogue
// re-splits fp32 acc into hi/lo bf16.  z=2 (V): 1-pass, B staged from fp32 Wv
// with inline transpose+convert, epilogue writes Vt[bh][d][t] bf16.
// ---------------------------------------------------------------------------
__global__ __launch_bounds__(256)
void qkv_mfma(const u16* __restrict__ Xh, const u16* __restrict__ Xl,
              const u16* __restrict__ Wqh, const u16* __restrict__ Wql,
              const u16* __restrict__ Wkh, const u16* __restrict__ Wkl,
              const float* __restrict__ Wv,
              u16* __restrict__ Qh, u16* __restrict__ Ql,
              u16* __restrict__ Kh, u16* __restrict__ Kl,
              u16* __restrict__ Vt)
{
    const int z  = blockIdx.z;
    const int m0 = blockIdx.x * 128;
    const int n0 = blockIdx.y * 128;
    const int t    = threadIdx.x;
    const int wave = t >> 6, lane = t & 63;
    const int wm = wave & 1, wn = wave >> 1;
    const int l16 = lane & 15, quad = lane >> 4;

    __shared__ u16 Ahs[128][STR];
    __shared__ u16 Als[128][STR];
    __shared__ u16 Bhs[128][STR];
    __shared__ u16 Bls[128][STR];

    const u16* Bh_g = (z == 0) ? Wqh : Wkh;
    const u16* Bl_g = (z == 0) ? Wql : Wkl;

    // staging coords: chunks t and t+256 of 512 (8 elems each)
    const int ar0 = t >> 2,           ak0 = (t & 3) * 8;
    const int ar1 = (t + 256) >> 2,   ak1 = (t & 3) * 8;
    // z==2 B-staging coords
    const int vd = t & 63;            // d lane (coalesced Wv reads)
    const int vg = t >> 6;            // e-group of 8

    f32x4 acc[4][4];
#pragma unroll
    for (int i = 0; i < 4; ++i)
#pragma unroll
        for (int j = 0; j < 4; ++j) acc[i][j] = (f32x4){0.f, 0.f, 0.f, 0.f};

    for (int k0 = 0; k0 < EMB; k0 += 32) {
        bf16x8 a_h0, a_h1, a_l0, a_l1, b_h0, b_h1, b_l0, b_l1;
        unsigned vpack[8];
        a_h0 = *(const bf16x8*)(Xh + (size_t)(m0 + ar0) * EMB + k0 + ak0);
        a_h1 = *(const bf16x8*)(Xh + (size_t)(m0 + ar1) * EMB + k0 + ak1);
        if (z != 2) {
            a_l0 = *(const bf16x8*)(Xl + (size_t)(m0 + ar0) * EMB + k0 + ak0);
            a_l1 = *(const bf16x8*)(Xl + (size_t)(m0 + ar1) * EMB + k0 + ak1);
            b_h0 = *(const bf16x8*)(Bh_g + (size_t)(n0 + ar0) * EMB + k0 + ak0);
            b_h1 = *(const bf16x8*)(Bh_g + (size_t)(n0 + ar1) * EMB + k0 + ak1);
            b_l0 = *(const bf16x8*)(Bl_g + (size_t)(n0 + ar0) * EMB + k0 + ak0);
            b_l1 = *(const bf16x8*)(Bl_g + (size_t)(n0 + ar1) * EMB + k0 + ak1);
        } else {
            // Wv[h][e][d]: lane=d -> coalesced; pack e-pairs into u32
            const float* vsrc = Wv + ((size_t)(n0 >> 6) * EMB + k0 + vg * 8) * HDIM + vd;
#pragma unroll
            for (int hh = 0; hh < 2; ++hh)
#pragma unroll
                for (int p = 0; p < 4; ++p) {
                    float v0 = vsrc[(size_t)hh * EMB * HDIM + (p * 2 + 0) * HDIM];
                    float v1 = vsrc[(size_t)hh * EMB * HDIM + (p * 2 + 1) * HDIM];
                    vpack[hh * 4 + p] = (unsigned)f2bf(v0) | ((unsigned)f2bf(v1) << 16);
                }
        }
        __syncthreads();
        *(bf16x8*)&Ahs[ar0][ak0] = a_h0;  *(bf16x8*)&Ahs[ar1][ak1] = a_h1;
        if (z != 2) {
            *(bf16x8*)&Als[ar0][ak0] = a_l0;  *(bf16x8*)&Als[ar1][ak1] = a_l1;
            *(bf16x8*)&Bhs[ar0][ak0] = b_h0;  *(bf16x8*)&Bhs[ar1][ak1] = b_h1;
            *(bf16x8*)&Bls[ar0][ak0] = b_l0;  *(bf16x8*)&Bls[ar1][ak1] = b_l1;
        } else {
#pragma unroll
            for (int hh = 0; hh < 2; ++hh)
#pragma unroll
                for (int p = 0; p < 4; ++p)
                    *(unsigned*)&Bhs[hh * 64 + vd][vg * 8 + p * 2] = vpack[hh * 4 + p];
        }
        __syncthreads();

        bf16x8 B4h[4], B4l[4];
#pragma unroll
        for (int j = 0; j < 4; ++j)
            B4h[j] = *(const bf16x8*)&Bhs[wn * 64 + 16 * j + l16][quad * 8];
        if (z != 2) {
#pragma unroll
            for (int j = 0; j < 4; ++j)
                B4l[j] = *(const bf16x8*)&Bls[wn * 64 + 16 * j + l16][quad * 8];
        }
#pragma unroll
        for (int i = 0; i < 4; ++i) {
            bf16x8 Ai_h = *(const bf16x8*)&Ahs[wm * 64 + 16 * i + l16][quad * 8];
            if (z != 2) {
                bf16x8 Ai_l = *(const bf16x8*)&Als[wm * 64 + 16 * i + l16][quad * 8];
#pragma unroll
                for (int j = 0; j < 4; ++j) {
                    acc[i][j] = __builtin_amdgcn_mfma_f32_16x16x32_bf16(Ai_h, B4h[j], acc[i][j], 0, 0, 0);
                    acc[i][j] = __builtin_amdgcn_mfma_f32_16x16x32_bf16(Ai_h, B4l[j], acc[i][j], 0, 0, 0);
                    acc[i][j] = __builtin_amdgcn_mfma_f32_16x16x32_bf16(Ai_l, B4h[j], acc[i][j], 0, 0, 0);
                }
            } else {
#pragma unroll
                for (int j = 0; j < 4; ++j)
                    acc[i][j] = __builtin_amdgcn_mfma_f32_16x16x32_bf16(Ai_h, B4h[j], acc[i][j], 0, 0, 0);
            }
        }
    }

    // epilogue.  m-rows of this block are within one batch (128 | 2048).
    const int b = m0 >> 11;
    const int h = (n0 + wn * 64) >> 6;   // head is wave-uniform
    if (z != 2) {
        u16* Oh = z ? Kh : Qh;
        u16* Ol = z ? Kl : Ql;
#pragma unroll
        for (int i = 0; i < 4; ++i)
#pragma unroll
            for (int r = 0; r < 4; ++r) {
                int tt = (m0 & (SEQ - 1)) + wm * 64 + 16 * i + quad * 4 + r;
                size_t rowbase = ((size_t)(b * HEADS + h) * SEQ + tt) * HDIM;
#pragma unroll
                for (int j = 0; j < 4; ++j) {
                    int d = 16 * j + l16;
                    float v = acc[i][j][r];
                    u16 hv = f2bf(v);
                    Oh[rowbase + d] = hv;
                    Ol[rowbase + d] = f2bf(v - bf2f(hv));
                }
            }
    } else {
#pragma unroll
        for (int i = 0; i < 4; ++i)
#pragma unroll
            for (int j = 0; j < 4; ++j) {
                int d  = 16 * j + l16;
                int tt = (m0 & (SEQ - 1)) + wm * 64 + 16 * i + quad * 4;
                ushort4 o;
                o.x = f2bf(acc[i][j][0]); o.y = f2bf(acc[i][j][1]);
                o.z = f2bf(acc[i][j][2]); o.w = f2bf(acc[i][j][3]);
                *(ushort4*)(Vt + ((size_t)(b * HEADS + h) * HDIM + d) * SEQ + tt) = o;
            }
    }
}

// ---------------------------------------------------------------------------
// Kernel 2: flash attention, MFMA 16x16x32 bf16 (unchanged from R2).
// ---------------------------------------------------------------------------
__global__ __launch_bounds__(256)
void attn_mfma(const u16* __restrict__ Qh, const u16* __restrict__ Ql,
               const u16* __restrict__ Kh, const u16* __restrict__ Kl,
               const u16* __restrict__ Vt, u16* __restrict__ Cb)
{
    const int qt0  = blockIdx.x * 64;
    const int bh   = blockIdx.y;
    const int t    = threadIdx.x;
    const int wave = t >> 6;
    const int lane = t & 63;
    const int l16  = lane & 15;
    const int quad = lane >> 4;

    __shared__ u16 Ksh[64][72];
    __shared__ u16 Ksl[64][72];
    __shared__ u16 Vs [64][72];
    __shared__ u16 Ps [64][72];

    const size_t bh_off = (size_t)bh * SEQ * HDIM;
    const u16* Qhb = Qh + bh_off;
    const u16* Qlb = Ql + bh_off;
    const u16* Khb = Kh + bh_off;
    const u16* Klb = Kl + bh_off;
    const u16* Vtb = Vt + bh_off;

    bf16x8 aQh[2], aQl[2];
    {
        const int qrow = qt0 + wave * 16 + l16;
        const u16* bH = Qhb + (size_t)qrow * HDIM + quad * 8;
        const u16* bL = Qlb + (size_t)qrow * HDIM + quad * 8;
        aQh[0] = *(const bf16x8*)(bH);
        aQh[1] = *(const bf16x8*)(bH + 32);
        aQl[0] = *(const bf16x8*)(bL);
        aQl[1] = *(const bf16x8*)(bL + 32);
    }

    f32x4 accO[4];
    float m_i[4], l_i[4];
#pragma unroll
    for (int j = 0; j < 4; ++j) { accO[j] = (f32x4){0.f, 0.f, 0.f, 0.f}; }
#pragma unroll
    for (int r = 0; r < 4; ++r) { m_i[r] = -1e30f; l_i[r] = 0.f; }

    const int ch0 = t, ch1 = t + 256;
    const int r0 = ch0 >> 3, c0 = (ch0 & 7) * 8;
    const int r1 = ch1 >> 3, c1 = (ch1 & 7) * 8;

    for (int s0 = 0; s0 < SEQ; s0 += 64) {
        bf16x8 kh0 = *(const bf16x8*)(Khb + (size_t)(s0 + r0) * HDIM + c0);
        bf16x8 kh1 = *(const bf16x8*)(Khb + (size_t)(s0 + r1) * HDIM + c1);
        bf16x8 kl0 = *(const bf16x8*)(Klb + (size_t)(s0 + r0) * HDIM + c0);
        bf16x8 kl1 = *(const bf16x8*)(Klb + (size_t)(s0 + r1) * HDIM + c1);
        bf16x8 vv0 = *(const bf16x8*)(Vtb + (size_t)r0 * SEQ + s0 + c0);
        bf16x8 vv1 = *(const bf16x8*)(Vtb + (size_t)r1 * SEQ + s0 + c1);
        __syncthreads();
        *(bf16x8*)&Ksh[r0][c0] = kh0;  *(bf16x8*)&Ksh[r1][c1] = kh1;
        *(bf16x8*)&Ksl[r0][c0] = kl0;  *(bf16x8*)&Ksl[r1][c1] = kl1;
        *(bf16x8*)&Vs [r0][c0] = vv0;  *(bf16x8*)&Vs [r1][c1] = vv1;
        __syncthreads();

        f32x4 accS[4];
#pragma unroll
        for (int j = 0; j < 4; ++j) accS[j] = (f32x4){0.f, 0.f, 0.f, 0.f};
#pragma unroll
        for (int c = 0; c < 2; ++c) {
#pragma unroll
            for (int j = 0; j < 4; ++j) {
                bf16x8 bh_ = *(const bf16x8*)&Ksh[16 * j + l16][c * 32 + quad * 8];
                bf16x8 bl_ = *(const bf16x8*)&Ksl[16 * j + l16][c * 32 + quad * 8];
                accS[j] = __builtin_amdgcn_mfma_f32_16x16x32_bf16(aQh[c], bh_, accS[j], 0, 0, 0);
                accS[j] = __builtin_amdgcn_mfma_f32_16x16x32_bf16(aQh[c], bl_, accS[j], 0, 0, 0);
                accS[j] = __builtin_amdgcn_mfma_f32_16x16x32_bf16(aQl[c], bh_, accS[j], 0, 0, 0);
            }
        }
#pragma unroll
        for (int j = 0; j < 4; ++j) accS[j] *= 0.125f;

        float P[4][4];
#pragma unroll
        for (int r = 0; r < 4; ++r) {
            float v = fmaxf(fmaxf(accS[0][r], accS[1][r]),
                            fmaxf(accS[2][r], accS[3][r]));
#pragma unroll
            for (int mk = 1; mk < 16; mk <<= 1) v = fmaxf(v, __shfl_xor(v, mk, 64));
            float mn   = fmaxf(m_i[r], v);
            float alph = __expf(m_i[r] - mn);
            m_i[r] = mn;
            float s = 0.f;
#pragma unroll
            for (int j = 0; j < 4; ++j) { P[j][r] = __expf(accS[j][r] - mn); s += P[j][r]; }
#pragma unroll
            for (int mk = 1; mk < 16; mk <<= 1) s += __shfl_xor(s, mk, 64);
            l_i[r] = l_i[r] * alph + s;
#pragma unroll
            for (int j = 0; j < 4; ++j) accO[j][r] *= alph;
        }

#pragma unroll
        for (int r = 0; r < 4; ++r)
#pragma unroll
            for (int j = 0; j < 4; ++j)
                Ps[wave * 16 + quad * 4 + r][16 * j + l16] = f2bf(P[j][r]);

#pragma unroll
        for (int c = 0; c < 2; ++c) {
            bf16x8 aP = *(const bf16x8*)&Ps[wave * 16 + l16][c * 32 + quad * 8];
#pragma unroll
            for (int j = 0; j < 4; ++j) {
                bf16x8 bV = *(const bf16x8*)&Vs[16 * j + l16][c * 32 + quad * 8];
                accO[j] = __builtin_amdgcn_mfma_f32_16x16x32_bf16(aP, bV, accO[j], 0, 0, 0);
            }
        }
    }

    const int b = bh >> 4, h = bh & 15;
#pragma unroll
    for (int r = 0; r < 4; ++r) {
        float inv = 1.f / l_i[r];
        int  row  = qt0 + wave * 16 + quad * 4 + r;
#pragma unroll
        for (int j = 0; j < 4; ++j) {
            int col = h * HDIM + 16 * j + l16;
            Cb[((size_t)b * SEQ + row) * EMB + col] = f2bf(accO[j][r] * inv);
        }
    }
}

// ---------------------------------------------------------------------------
// Kernel 3: Y = X + C @ Wo^T, bf16 MFMA (unchanged from R2).
// ---------------------------------------------------------------------------
__global__ __launch_bounds__(256)
void oproj_mfma(const u16* __restrict__ Cb, const u16* __restrict__ Woh,
                const float* __restrict__ X, float* __restrict__ Y)
{
    const int m0 = blockIdx.x * 64, n0 = blockIdx.y * 64;
    const int t    = threadIdx.x;
    const int wave = t >> 6;
    const int lane = t & 63;
    const int l16  = lane & 15;
    const int quad = lane >> 4;

    __shared__ u16 As[64][72];
    __shared__ u16 Bs[64][72];

    const int ch0 = t, ch1 = t + 256;
    const int r0 = ch0 >> 3, c0 = (ch0 & 7) * 8;
    const int r1 = ch1 >> 3, c1 = (ch1 & 7) * 8;

    f32x4 acc[4];
#pragma unroll
    for (int j = 0; j < 4; ++j) acc[j] = (f32x4){0.f, 0.f, 0.f, 0.f};

    for (int k0 = 0; k0 < EMB; k0 += 64) {
        bf16x8 a0 = *(const bf16x8*)(Cb  + (size_t)(m0 + r0) * EMB + k0 + c0);
        bf16x8 a1 = *(const bf16x8*)(Cb  + (size_t)(m0 + r1) * EMB + k0 + c1);
        bf16x8 b0 = *(const bf16x8*)(Woh + (size_t)(n0 + r0) * EMB + k0 + c0);
        bf16x8 b1 = *(const bf16x8*)(Woh + (size_t)(n0 + r1) * EMB + k0 + c1);
        __syncthreads();
        *(bf16x8*)&As[r0][c0] = a0;  *(bf16x8*)&As[r1][c1] = a1;
        *(bf16x8*)&Bs[r0][c0] = b0;  *(bf16x8*)&Bs[r1][c1] = b1;
        __syncthreads();
#pragma unroll
        for (int c = 0; c < 2; ++c) {
            bf16x8 aA = *(const bf16x8*)&As[wave * 16 + l16][c * 32 + quad * 8];
#pragma unroll
            for (int j = 0; j < 4; ++j) {
                bf16x8 bB = *(const bf16x8*)&Bs[16 * j + l16][c * 32 + quad * 8];
                acc[j] = __builtin_amdgcn_mfma_f32_16x16x32_bf16(aA, bB, acc[j], 0, 0, 0);
            }
        }
    }

#pragma unroll
    for (int r = 0; r < 4; ++r) {
        int m = m0 + wave * 16 + quad * 4 + r;
#pragma unroll
        for (int j = 0; j < 4; ++j) {
            int n = n0 + 16 * j + l16;
            Y[(size_t)m * EMB + n] = acc[j][r] + X[(size_t)m * EMB + n];
        }
    }
}

// ---------------------------------------------------------------------------
// Workspace map (exactly 64 MiB = 33,554,432 u16; R1 proved ws >= this):
//   [0]        Qh  4M    [4M]  Ql   [8M]  Kh   [12M] Kl   [16M] Vt
//   [20M]      Xh  4M    (aliased by Cb after qkv)
//   [24M]      Xl  4M    (aliased by Woh after qkv)
//   [28M]      Wtq_h 1M, Wtq_l 1M, Wtk_h 1M, Wtk_l 1M
// ---------------------------------------------------------------------------
extern "C" void kernel_launch(void* const* d_in, const int* in_sizes, int n_in,
                              void* d_out, int out_size, void* d_ws,
                              size_t ws_size, hipStream_t stream)
{
    const float* x  = (const float*)d_in[0];
    const float* Wq = (const float*)d_in[1];
    const float* Wk = (const float*)d_in[2];
    const float* Wv = (const float*)d_in[3];
    const float* Wo = (const float*)d_in[4];
    float* Y = (float*)d_out;

    const size_t NPER = (size_t)MROWS * EMB;   // 4,194,304
    u16* base = (u16*)d_ws;
    u16* Qh   = base;
    u16* Ql   = Qh + NPER;
    u16* Kh   = Ql + NPER;
    u16* Kl   = Kh + NPER;
    u16* Vt   = Kl + NPER;
    u16* Xh   = Vt + NPER;
    u16* Xl   = Xh + NPER;
    u16* Wtq_h = Xl + NPER;
    u16* Wtq_l = Wtq_h + EMB * EMB;
    u16* Wtk_h = Wtq_l + EMB * EMB;
    u16* Wtk_l = Wtk_h + EMB * EMB;
    u16* Cb   = Xh;   // alias: Xh dead after qkv
    u16* Woh  = Xl;   // alias: Xl dead after qkv (conv launched after qkv)

    xsplit<<<dim3(NPER / 2048), 256, 0, stream>>>(x, Xh, Xl);
    wtrans<<<dim3(32, 16, 2), 256, 0, stream>>>(Wq, Wk, Wtq_h, Wtq_l,
                                                Wtk_h, Wtk_l);
    qkv_mfma<<<dim3(32, 8, 3), 256, 0, stream>>>(Xh, Xl, Wtq_h, Wtq_l,
                                                 Wtk_h, Wtk_l, Wv,
                                                 Qh, Ql, Kh, Kl, Vt);
    conv_bf16<<<dim3(EMB * EMB / 1024), 256, 0, stream>>>(Wo, Woh);
    attn_mfma<<<dim3(SEQ / 64, BATCH * HEADS), 256, 0, stream>>>(Qh, Ql, Kh, Kl,
                                                                 Vt, Cb);
    oproj_mfma<<<dim3(MROWS / 64, EMB / 64), 256, 0, stream>>>(Cb, Woh, x, Y);
}

// Round 4
// 348.613 us; speedup vs baseline: 3.1227x; 1.1221x over previous
//
#include <hip/hip_runtime.h>

#define EMB   1024
#define HEADS 16
#define HDIM  64
#define BATCH 2
#define SEQ   2048
#define MROWS (BATCH*SEQ)   // 4096
#define STR   40            // LDS k-stride in u16: 80 B

typedef __attribute__((ext_vector_type(8))) short bf16x8;   // 8 bf16 (4 VGPRs)
typedef __attribute__((ext_vector_type(4))) float f32x4;    // MFMA C/D
typedef unsigned short u16;

__device__ __forceinline__ u16 f2bf(float f) {              // round-to-nearest-even
    unsigned u = __float_as_uint(f);
    u += 0x7fffu + ((u >> 16) & 1u);
    return (u16)(u >> 16);
}
__device__ __forceinline__ float bf2f(u16 h) {
    return __uint_as_float((unsigned)h << 16);
}

// ---------------------------------------------------------------------------
// X -> Xh/Xl bf16 split.
// ---------------------------------------------------------------------------
__global__ __launch_bounds__(256)
void xsplit(const float* __restrict__ X, u16* __restrict__ Xh,
            u16* __restrict__ Xl)
{
    int i = (blockIdx.x * 256 + threadIdx.x) * 8;
#pragma unroll
    for (int half = 0; half < 2; ++half) {
        float4 v = *(const float4*)(X + i + half * 4);
        ushort4 hi, lo;
        hi.x = f2bf(v.x); lo.x = f2bf(v.x - bf2f(hi.x));
        hi.y = f2bf(v.y); lo.y = f2bf(v.y - bf2f(hi.y));
        hi.z = f2bf(v.z); lo.z = f2bf(v.z - bf2f(hi.z));
        hi.w = f2bf(v.w); lo.w = f2bf(v.w - bf2f(hi.w));
        *(ushort4*)(Xh + i + half * 4) = hi;
        *(ushort4*)(Xl + i + half * 4) = lo;
    }
}

// ---------------------------------------------------------------------------
// Wq/Wk [16][1024][64] -> transposed hi/lo bf16 [h*64+d][e].  grid (32,16,2).
// ---------------------------------------------------------------------------
__global__ __launch_bounds__(256)
void wtrans(const float* __restrict__ Wq, const float* __restrict__ Wk,
            u16* __restrict__ Qth, u16* __restrict__ Qtl,
            u16* __restrict__ Kth, u16* __restrict__ Ktl)
{
    const float* W  = blockIdx.z ? Wk  : Wq;
    u16* Oh         = blockIdx.z ? Kth : Qth;
    u16* Ol         = blockIdx.z ? Ktl : Qtl;
    const int h  = blockIdx.y;
    const int d  = threadIdx.x & 63;
    const int e0 = (blockIdx.x * 4 + (threadIdx.x >> 6)) * 8;

    const float* src = W + ((size_t)h * EMB + e0) * HDIM + d;
    ushort4 h0, h1, l0, l1;
    float v; u16 hv;
    v = src[0 * 64]; hv = f2bf(v); h0.x = hv; l0.x = f2bf(v - bf2f(hv));
    v = src[1 * 64]; hv = f2bf(v); h0.y = hv; l0.y = f2bf(v - bf2f(hv));
    v = src[2 * 64]; hv = f2bf(v); h0.z = hv; l0.z = f2bf(v - bf2f(hv));
    v = src[3 * 64]; hv = f2bf(v); h0.w = hv; l0.w = f2bf(v - bf2f(hv));
    v = src[4 * 64]; hv = f2bf(v); h1.x = hv; l1.x = f2bf(v - bf2f(hv));
    v = src[5 * 64]; hv = f2bf(v); h1.y = hv; l1.y = f2bf(v - bf2f(hv));
    v = src[6 * 64]; hv = f2bf(v); h1.z = hv; l1.z = f2bf(v - bf2f(hv));
    v = src[7 * 64]; hv = f2bf(v); h1.w = hv; l1.w = f2bf(v - bf2f(hv));

    size_t obase = ((size_t)h * HDIM + d) * EMB + e0;
    *(ushort4*)(Oh + obase)     = h0;
    *(ushort4*)(Oh + obase + 4) = h1;
    *(ushort4*)(Ol + obase)     = l0;
    *(ushort4*)(Ol + obase + 4) = l1;
}

// ---------------------------------------------------------------------------
// Wv [16][1024][64] -> transposed bf16 (hi only) [h*64+d][e].  grid (32,16).
// ---------------------------------------------------------------------------
__global__ __launch_bounds__(256)
void wtrans_v(const float* __restrict__ Wv, u16* __restrict__ Vth)
{
    const int h  = blockIdx.y;
    const int d  = threadIdx.x & 63;
    const int e0 = (blockIdx.x * 4 + (threadIdx.x >> 6)) * 8;
    const float* src = Wv + ((size_t)h * EMB + e0) * HDIM + d;
    ushort4 h0, h1;
    h0.x = f2bf(src[0 * 64]); h0.y = f2bf(src[1 * 64]);
    h0.z = f2bf(src[2 * 64]); h0.w = f2bf(src[3 * 64]);
    h1.x = f2bf(src[4 * 64]); h1.y = f2bf(src[5 * 64]);
    h1.z = f2bf(src[6 * 64]); h1.w = f2bf(src[7 * 64]);
    size_t obase = ((size_t)h * HDIM + d) * EMB + e0;
    *(ushort4*)(Vth + obase)     = h0;
    *(ushort4*)(Vth + obase + 4) = h1;
}

// ---------------------------------------------------------------------------
// Wo -> bf16 elementwise.
// ---------------------------------------------------------------------------
__global__ __launch_bounds__(256)
void conv_bf16(const float* __restrict__ src, u16* __restrict__ dst)
{
    int i = (blockIdx.x * 256 + threadIdx.x) * 4;
    float4 v = *(const float4*)(src + i);
    ushort4 o;
    o.x = f2bf(v.x); o.y = f2bf(v.y); o.z = f2bf(v.z); o.w = f2bf(v.w);
    *(ushort4*)(dst + i) = o;
}

// ---------------------------------------------------------------------------
// Kernel 1a: Q/K projection, 3-pass split-bf16, software-pipelined.
// grid (32, 8, 2), block 256 = 2x2 waves, tile 128x128, BK=32.
// Loop: sync -> LDS-store(cur) -> sync -> load(k+1) -> compute(k) -> rotate.
// ---------------------------------------------------------------------------
__global__ __launch_bounds__(256)
void qkv_z01(const u16* __restrict__ Xh, const u16* __restrict__ Xl,
             const u16* __restrict__ Wqh, const u16* __restrict__ Wql,
             const u16* __restrict__ Wkh, const u16* __restrict__ Wkl,
             u16* __restrict__ Qh, u16* __restrict__ Ql,
             u16* __restrict__ Kh, u16* __restrict__ Kl)
{
    const int z  = blockIdx.z;
    const int m0 = blockIdx.x * 128;
    const int n0 = blockIdx.y * 128;
    const int t    = threadIdx.x;
    const int wave = t >> 6, lane = t & 63;
    const int wm = wave & 1, wn = wave >> 1;
    const int l16 = lane & 15, quad = lane >> 4;

    __shared__ u16 Ahs[128][STR];
    __shared__ u16 Als[128][STR];
    __shared__ u16 Bhs[128][STR];
    __shared__ u16 Bls[128][STR];

    const u16* Bh_g = z ? Wkh : Wqh;
    const u16* Bl_g = z ? Wkl : Wql;

    const int ar0 = t >> 2, ak = (t & 3) * 8, ar1 = ar0 + 64;

    f32x4 acc[4][4];
#pragma unroll
    for (int i = 0; i < 4; ++i)
#pragma unroll
        for (int j = 0; j < 4; ++j) acc[i][j] = (f32x4){0.f, 0.f, 0.f, 0.f};

    bf16x8 cur[8], nxt[8];
#define QK_LOAD(dst, kk)                                                        \
    do {                                                                        \
        dst[0] = *(const bf16x8*)(Xh  + (size_t)(m0 + ar0) * EMB + (kk) + ak);  \
        dst[1] = *(const bf16x8*)(Xh  + (size_t)(m0 + ar1) * EMB + (kk) + ak);  \
        dst[2] = *(const bf16x8*)(Xl  + (size_t)(m0 + ar0) * EMB + (kk) + ak);  \
        dst[3] = *(const bf16x8*)(Xl  + (size_t)(m0 + ar1) * EMB + (kk) + ak);  \
        dst[4] = *(const bf16x8*)(Bh_g + (size_t)(n0 + ar0) * EMB + (kk) + ak); \
        dst[5] = *(const bf16x8*)(Bh_g + (size_t)(n0 + ar1) * EMB + (kk) + ak); \
        dst[6] = *(const bf16x8*)(Bl_g + (size_t)(n0 + ar0) * EMB + (kk) + ak); \
        dst[7] = *(const bf16x8*)(Bl_g + (size_t)(n0 + ar1) * EMB + (kk) + ak); \
    } while (0)

    QK_LOAD(cur, 0);

    for (int k0 = 0; k0 < EMB; k0 += 32) {
        __syncthreads();
        *(bf16x8*)&Ahs[ar0][ak] = cur[0];  *(bf16x8*)&Ahs[ar1][ak] = cur[1];
        *(bf16x8*)&Als[ar0][ak] = cur[2];  *(bf16x8*)&Als[ar1][ak] = cur[3];
        *(bf16x8*)&Bhs[ar0][ak] = cur[4];  *(bf16x8*)&Bhs[ar1][ak] = cur[5];
        *(bf16x8*)&Bls[ar0][ak] = cur[6];  *(bf16x8*)&Bls[ar1][ak] = cur[7];
        __syncthreads();

        const int kn = (k0 + 32 < EMB) ? k0 + 32 : 0;   // dummy reload on last
        QK_LOAD(nxt, kn);

        bf16x8 B4h[4], B4l[4];
#pragma unroll
        for (int j = 0; j < 4; ++j) {
            B4h[j] = *(const bf16x8*)&Bhs[wn * 64 + 16 * j + l16][quad * 8];
            B4l[j] = *(const bf16x8*)&Bls[wn * 64 + 16 * j + l16][quad * 8];
        }
#pragma unroll
        for (int i = 0; i < 4; ++i) {
            bf16x8 Ai_h = *(const bf16x8*)&Ahs[wm * 64 + 16 * i + l16][quad * 8];
            bf16x8 Ai_l = *(const bf16x8*)&Als[wm * 64 + 16 * i + l16][quad * 8];
#pragma unroll
            for (int j = 0; j < 4; ++j) {
                acc[i][j] = __builtin_amdgcn_mfma_f32_16x16x32_bf16(Ai_h, B4h[j], acc[i][j], 0, 0, 0);
                acc[i][j] = __builtin_amdgcn_mfma_f32_16x16x32_bf16(Ai_h, B4l[j], acc[i][j], 0, 0, 0);
                acc[i][j] = __builtin_amdgcn_mfma_f32_16x16x32_bf16(Ai_l, B4h[j], acc[i][j], 0, 0, 0);
            }
        }
#pragma unroll
        for (int q = 0; q < 8; ++q) cur[q] = nxt[q];
    }
#undef QK_LOAD

    const int b = m0 >> 11;
    const int h = (n0 + wn * 64) >> 6;
    u16* Oh = z ? Kh : Qh;
    u16* Ol = z ? Kl : Ql;
#pragma unroll
    for (int i = 0; i < 4; ++i)
#pragma unroll
        for (int r = 0; r < 4; ++r) {
            int tt = (m0 & (SEQ - 1)) + wm * 64 + 16 * i + quad * 4 + r;
            size_t rowbase = ((size_t)(b * HEADS + h) * SEQ + tt) * HDIM;
#pragma unroll
            for (int j = 0; j < 4; ++j) {
                int d = 16 * j + l16;
                float v = acc[i][j][r];
                u16 hv = f2bf(v);
                Oh[rowbase + d] = hv;
                Ol[rowbase + d] = f2bf(v - bf2f(hv));
            }
        }
}

// ---------------------------------------------------------------------------
// Kernel 1b: V projection, 1-pass bf16, pipelined.  grid (32, 8), block 256.
// B = Wvt (pre-transposed bf16) -> contiguous staging like Q/K.
// Epilogue writes Vt[bh][d][t] (transposed for attention's PV B-operand).
// ---------------------------------------------------------------------------
__global__ __launch_bounds__(256)
void qkv_v(const u16* __restrict__ Xh, const u16* __restrict__ Wvt,
           u16* __restrict__ Vt)
{
    const int m0 = blockIdx.x * 128;
    const int n0 = blockIdx.y * 128;
    const int t    = threadIdx.x;
    const int wave = t >> 6, lane = t & 63;
    const int wm = wave & 1, wn = wave >> 1;
    const int l16 = lane & 15, quad = lane >> 4;

    __shared__ u16 Ahs[128][STR];
    __shared__ u16 Bhs[128][STR];

    const int ar0 = t >> 2, ak = (t & 3) * 8, ar1 = ar0 + 64;

    f32x4 acc[4][4];
#pragma unroll
    for (int i = 0; i < 4; ++i)
#pragma unroll
        for (int j = 0; j < 4; ++j) acc[i][j] = (f32x4){0.f, 0.f, 0.f, 0.f};

    bf16x8 cur[4], nxt[4];
#define V_LOAD(dst, kk)                                                         \
    do {                                                                        \
        dst[0] = *(const bf16x8*)(Xh  + (size_t)(m0 + ar0) * EMB + (kk) + ak);  \
        dst[1] = *(const bf16x8*)(Xh  + (size_t)(m0 + ar1) * EMB + (kk) + ak);  \
        dst[2] = *(const bf16x8*)(Wvt + (size_t)(n0 + ar0) * EMB + (kk) + ak);  \
        dst[3] = *(const bf16x8*)(Wvt + (size_t)(n0 + ar1) * EMB + (kk) + ak);  \
    } while (0)

    V_LOAD(cur, 0);

    for (int k0 = 0; k0 < EMB; k0 += 32) {
        __syncthreads();
        *(bf16x8*)&Ahs[ar0][ak] = cur[0];  *(bf16x8*)&Ahs[ar1][ak] = cur[1];
        *(bf16x8*)&Bhs[ar0][ak] = cur[2];  *(bf16x8*)&Bhs[ar1][ak] = cur[3];
        __syncthreads();

        const int kn = (k0 + 32 < EMB) ? k0 + 32 : 0;
        V_LOAD(nxt, kn);

        bf16x8 B4[4];
#pragma unroll
        for (int j = 0; j < 4; ++j)
            B4[j] = *(const bf16x8*)&Bhs[wn * 64 + 16 * j + l16][quad * 8];
#pragma unroll
        for (int i = 0; i < 4; ++i) {
            bf16x8 Ai = *(const bf16x8*)&Ahs[wm * 64 + 16 * i + l16][quad * 8];
#pragma unroll
            for (int j = 0; j < 4; ++j)
                acc[i][j] = __builtin_amdgcn_mfma_f32_16x16x32_bf16(Ai, B4[j], acc[i][j], 0, 0, 0);
        }
#pragma unroll
        for (int q = 0; q < 4; ++q) cur[q] = nxt[q];
    }
#undef V_LOAD

    const int b = m0 >> 11;
    const int h = (n0 + wn * 64) >> 6;
#pragma unroll
    for (int i = 0; i < 4; ++i)
#pragma unroll
        for (int j = 0; j < 4; ++j) {
            int d  = 16 * j + l16;
            int tt = (m0 & (SEQ - 1)) + wm * 64 + 16 * i + quad * 4;
            ushort4 o;
            o.x = f2bf(acc[i][j][0]); o.y = f2bf(acc[i][j][1]);
            o.z = f2bf(acc[i][j][2]); o.w = f2bf(acc[i][j][3]);
            *(ushort4*)(Vt + ((size_t)(b * HEADS + h) * HDIM + d) * SEQ + tt) = o;
        }
}

// ---------------------------------------------------------------------------
// Kernel 2: flash attention, MFMA, software-pipelined K/V prefetch.
// ---------------------------------------------------------------------------
__global__ __launch_bounds__(256)
void attn_mfma(const u16* __restrict__ Qh, const u16* __restrict__ Ql,
               const u16* __restrict__ Kh, const u16* __restrict__ Kl,
               const u16* __restrict__ Vt, u16* __restrict__ Cb)
{
    const int qt0  = blockIdx.x * 64;
    const int bh   = blockIdx.y;
    const int t    = threadIdx.x;
    const int wave = t >> 6;
    const int lane = t & 63;
    const int l16  = lane & 15;
    const int quad = lane >> 4;

    __shared__ u16 Ksh[64][72];
    __shared__ u16 Ksl[64][72];
    __shared__ u16 Vs [64][72];
    __shared__ u16 Ps [64][72];

    const size_t bh_off = (size_t)bh * SEQ * HDIM;
    const u16* Qhb = Qh + bh_off;
    const u16* Qlb = Ql + bh_off;
    const u16* Khb = Kh + bh_off;
    const u16* Klb = Kl + bh_off;
    const u16* Vtb = Vt + bh_off;

    bf16x8 aQh[2], aQl[2];
    {
        const int qrow = qt0 + wave * 16 + l16;
        const u16* bH = Qhb + (size_t)qrow * HDIM + quad * 8;
        const u16* bL = Qlb + (size_t)qrow * HDIM + quad * 8;
        aQh[0] = *(const bf16x8*)(bH);
        aQh[1] = *(const bf16x8*)(bH + 32);
        aQl[0] = *(const bf16x8*)(bL);
        aQl[1] = *(const bf16x8*)(bL + 32);
    }

    f32x4 accO[4];
    float m_i[4], l_i[4];
#pragma unroll
    for (int j = 0; j < 4; ++j) { accO[j] = (f32x4){0.f, 0.f, 0.f, 0.f}; }
#pragma unroll
    for (int r = 0; r < 4; ++r) { m_i[r] = -1e30f; l_i[r] = 0.f; }

    const int r0 = t >> 3,          c0 = (t & 7) * 8;
    const int r1 = (t + 256) >> 3,  c1 = (t & 7) * 8;

    bf16x8 cur[6], nxt[6];
#define KV_LOAD(dst, ss)                                                       \
    do {                                                                       \
        dst[0] = *(const bf16x8*)(Khb + (size_t)((ss) + r0) * HDIM + c0);      \
        dst[1] = *(const bf16x8*)(Khb + (size_t)((ss) + r1) * HDIM + c1);      \
        dst[2] = *(const bf16x8*)(Klb + (size_t)((ss) + r0) * HDIM + c0);      \
        dst[3] = *(const bf16x8*)(Klb + (size_t)((ss) + r1) * HDIM + c1);      \
        dst[4] = *(const bf16x8*)(Vtb + (size_t)r0 * SEQ + (ss) + c0);         \
        dst[5] = *(const bf16x8*)(Vtb + (size_t)r1 * SEQ + (ss) + c1);         \
    } while (0)

    KV_LOAD(cur, 0);

    for (int s0 = 0; s0 < SEQ; s0 += 64) {
        __syncthreads();
        *(bf16x8*)&Ksh[r0][c0] = cur[0];  *(bf16x8*)&Ksh[r1][c1] = cur[1];
        *(bf16x8*)&Ksl[r0][c0] = cur[2];  *(bf16x8*)&Ksl[r1][c1] = cur[3];
        *(bf16x8*)&Vs [r0][c0] = cur[4];  *(bf16x8*)&Vs [r1][c1] = cur[5];
        __syncthreads();

        const int sn = (s0 + 64 < SEQ) ? s0 + 64 : 0;
        KV_LOAD(nxt, sn);

        f32x4 accS[4];
#pragma unroll
        for (int j = 0; j < 4; ++j) accS[j] = (f32x4){0.f, 0.f, 0.f, 0.f};
#pragma unroll
        for (int c = 0; c < 2; ++c) {
#pragma unroll
            for (int j = 0; j < 4; ++j) {
                bf16x8 bh_ = *(const bf16x8*)&Ksh[16 * j + l16][c * 32 + quad * 8];
                bf16x8 bl_ = *(const bf16x8*)&Ksl[16 * j + l16][c * 32 + quad * 8];
                accS[j] = __builtin_amdgcn_mfma_f32_16x16x32_bf16(aQh[c], bh_, accS[j], 0, 0, 0);
                accS[j] = __builtin_amdgcn_mfma_f32_16x16x32_bf16(aQh[c], bl_, accS[j], 0, 0, 0);
                accS[j] = __builtin_amdgcn_mfma_f32_16x16x32_bf16(aQl[c], bh_, accS[j], 0, 0, 0);
            }
        }
#pragma unroll
        for (int j = 0; j < 4; ++j) accS[j] *= 0.125f;

        float P[4][4];
#pragma unroll
        for (int r = 0; r < 4; ++r) {
            float v = fmaxf(fmaxf(accS[0][r], accS[1][r]),
                            fmaxf(accS[2][r], accS[3][r]));
#pragma unroll
            for (int mk = 1; mk < 16; mk <<= 1) v = fmaxf(v, __shfl_xor(v, mk, 64));
            float mn   = fmaxf(m_i[r], v);
            float alph = __expf(m_i[r] - mn);
            m_i[r] = mn;
            float s = 0.f;
#pragma unroll
            for (int j = 0; j < 4; ++j) { P[j][r] = __expf(accS[j][r] - mn); s += P[j][r]; }
#pragma unroll
            for (int mk = 1; mk < 16; mk <<= 1) s += __shfl_xor(s, mk, 64);
            l_i[r] = l_i[r] * alph + s;
#pragma unroll
            for (int j = 0; j < 4; ++j) accO[j][r] *= alph;
        }

#pragma unroll
        for (int r = 0; r < 4; ++r)
#pragma unroll
            for (int j = 0; j < 4; ++j)
                Ps[wave * 16 + quad * 4 + r][16 * j + l16] = f2bf(P[j][r]);

#pragma unroll
        for (int c = 0; c < 2; ++c) {
            bf16x8 aP = *(const bf16x8*)&Ps[wave * 16 + l16][c * 32 + quad * 8];
#pragma unroll
            for (int j = 0; j < 4; ++j) {
                bf16x8 bV = *(const bf16x8*)&Vs[16 * j + l16][c * 32 + quad * 8];
                accO[j] = __builtin_amdgcn_mfma_f32_16x16x32_bf16(aP, bV, accO[j], 0, 0, 0);
            }
        }
#pragma unroll
        for (int q = 0; q < 6; ++q) cur[q] = nxt[q];
    }
#undef KV_LOAD

    const int b = bh >> 4, h = bh & 15;
#pragma unroll
    for (int r = 0; r < 4; ++r) {
        float inv = 1.f / l_i[r];
        int  row  = qt0 + wave * 16 + quad * 4 + r;
#pragma unroll
        for (int j = 0; j < 4; ++j) {
            int col = h * HDIM + 16 * j + l16;
            Cb[((size_t)b * SEQ + row) * EMB + col] = f2bf(accO[j][r] * inv);
        }
    }
}

// ---------------------------------------------------------------------------
// Kernel 3: Y = X + C @ Wo^T, bf16 MFMA, pipelined.  grid (64, 16), 64x64.
// ---------------------------------------------------------------------------
__global__ __launch_bounds__(256)
void oproj_mfma(const u16* __restrict__ Cb, const u16* __restrict__ Woh,
                const float* __restrict__ X, float* __restrict__ Y)
{
    const int m0 = blockIdx.x * 64, n0 = blockIdx.y * 64;
    const int t    = threadIdx.x;
    const int wave = t >> 6;
    const int lane = t & 63;
    const int l16  = lane & 15;
    const int quad = lane >> 4;

    __shared__ u16 As[64][72];
    __shared__ u16 Bs[64][72];

    const int r0 = t >> 3,          c0 = (t & 7) * 8;
    const int r1 = (t + 256) >> 3,  c1 = (t & 7) * 8;

    f32x4 acc[4];
#pragma unroll
    for (int j = 0; j < 4; ++j) acc[j] = (f32x4){0.f, 0.f, 0.f, 0.f};

    bf16x8 cur[4], nxt[4];
#define O_LOAD(dst, kk)                                                        \
    do {                                                                       \
        dst[0] = *(const bf16x8*)(Cb  + (size_t)(m0 + r0) * EMB + (kk) + c0);  \
        dst[1] = *(const bf16x8*)(Cb  + (size_t)(m0 + r1) * EMB + (kk) + c1);  \
        dst[2] = *(const bf16x8*)(Woh + (size_t)(n0 + r0) * EMB + (kk) + c0);  \
        dst[3] = *(const bf16x8*)(Woh + (size_t)(n0 + r1) * EMB + (kk) + c1);  \
    } while (0)

    O_LOAD(cur, 0);

    for (int k0 = 0; k0 < EMB; k0 += 64) {
        __syncthreads();
        *(bf16x8*)&As[r0][c0] = cur[0];  *(bf16x8*)&As[r1][c1] = cur[1];
        *(bf16x8*)&Bs[r0][c0] = cur[2];  *(bf16x8*)&Bs[r1][c1] = cur[3];
        __syncthreads();

        const int kn = (k0 + 64 < EMB) ? k0 + 64 : 0;
        O_LOAD(nxt, kn);

#pragma unroll
        for (int c = 0; c < 2; ++c) {
            bf16x8 aA = *(const bf16x8*)&As[wave * 16 + l16][c * 32 + quad * 8];
#pragma unroll
            for (int j = 0; j < 4; ++j) {
                bf16x8 bB = *(const bf16x8*)&Bs[16 * j + l16][c * 32 + quad * 8];
                acc[j] = __builtin_amdgcn_mfma_f32_16x16x32_bf16(aA, bB, acc[j], 0, 0, 0);
            }
        }
#pragma unroll
        for (int q = 0; q < 4; ++q) cur[q] = nxt[q];
    }
#undef O_LOAD

#pragma unroll
    for (int r = 0; r < 4; ++r) {
        int m = m0 + wave * 16 + quad * 4 + r;
#pragma unroll
        for (int j = 0; j < 4; ++j) {
            int n = n0 + 16 * j + l16;
            Y[(size_t)m * EMB + n] = acc[j][r] + X[(size_t)m * EMB + n];
        }
    }
}

// ---------------------------------------------------------------------------
// Workspace map (u16 units, 32M total = 64 MiB):
//   [0]   Qh 4M   [4M] Ql   [8M] Kh   [12M] Kl   [16M] Vt
//   [20M] Xh 4M   (-> Cb after qkv_v)
//   [24M] Xl 4M   (-> Woh after qkv_z01)
//   [28M] Wtq_h 1M (-> Wvt after qkv_z01), [29M] Wtq_l, [30M] Wtk_h, [31M] Wtk_l
// Launch order makes every alias legal (stream is sequential).
// ---------------------------------------------------------------------------
extern "C" void kernel_launch(void* const* d_in, const int* in_sizes, int n_in,
                              void* d_out, int out_size, void* d_ws,
                              size_t ws_size, hipStream_t stream)
{
    const float* x  = (const float*)d_in[0];
    const float* Wq = (const float*)d_in[1];
    const float* Wk = (const float*)d_in[2];
    const float* Wv = (const float*)d_in[3];
    const float* Wo = (const float*)d_in[4];
    float* Y = (float*)d_out;

    const size_t NPER = (size_t)MROWS * EMB;   // 4,194,304
    u16* base  = (u16*)d_ws;
    u16* Qh    = base;
    u16* Ql    = Qh + NPER;
    u16* Kh    = Ql + NPER;
    u16* Kl    = Kh + NPER;
    u16* Vt    = Kl + NPER;
    u16* Xh    = Vt + NPER;
    u16* Xl    = Xh + NPER;
    u16* Wtq_h = Xl + NPER;
    u16* Wtq_l = Wtq_h + EMB * EMB;
    u16* Wtk_h = Wtq_l + EMB * EMB;
    u16* Wtk_l = Wtk_h + EMB * EMB;
    u16* Wvt   = Wtq_h;   // alias: Wtq dead after qkv_z01
    u16* Cb    = Xh;      // alias: Xh dead after qkv_v
    u16* Woh   = Xl;      // alias: Xl dead after qkv_z01

    xsplit<<<dim3(NPER / 2048), 256, 0, stream>>>(x, Xh, Xl);
    wtrans<<<dim3(32, 16, 2), 256, 0, stream>>>(Wq, Wk, Wtq_h, Wtq_l,
                                                Wtk_h, Wtk_l);
    qkv_z01<<<dim3(32, 8, 2), 256, 0, stream>>>(Xh, Xl, Wtq_h, Wtq_l,
                                                Wtk_h, Wtk_l, Qh, Ql, Kh, Kl);
    wtrans_v<<<dim3(32, 16), 256, 0, stream>>>(Wv, Wvt);
    conv_bf16<<<dim3(EMB * EMB / 1024), 256, 0, stream>>>(Wo, Woh);
    qkv_v<<<dim3(32, 8), 256, 0, stream>>>(Xh, Wvt, Vt);
    attn_mfma<<<dim3(SEQ / 64, BATCH * HEADS), 256, 0, stream>>>(Qh, Ql, Kh, Kl,
                                                                 Vt, Cb);
    oproj_mfma<<<dim3(MROWS / 64, EMB / 64), 256, 0, stream>>>(Cb, Woh, x, Y);
}

// Round 5
// 297.877 us; speedup vs baseline: 3.6546x; 1.1703x over previous
//
#include <hip/hip_runtime.h>

#define EMB   1024
#define HEADS 16
#define HDIM  64
#define BATCH 2
#define SEQ   2048
#define MROWS (BATCH*SEQ)   // 4096
#define STR   40            // LDS k-stride in u16: 80 B

typedef __attribute__((ext_vector_type(8))) short bf16x8;   // 8 bf16 (4 VGPRs)
typedef __attribute__((ext_vector_type(4))) float f32x4;    // MFMA C/D
typedef unsigned short u16;

__device__ __forceinline__ u16 f2bf(float f) {              // round-to-nearest-even
    unsigned u = __float_as_uint(f);
    u += 0x7fffu + ((u >> 16) & 1u);
    return (u16)(u >> 16);
}
__device__ __forceinline__ float bf2f(u16 h) {
    return __uint_as_float((unsigned)h << 16);
}

// ---------------------------------------------------------------------------
// X -> Xh/Xl bf16 split.
// ---------------------------------------------------------------------------
__global__ __launch_bounds__(256)
void xsplit(const float* __restrict__ X, u16* __restrict__ Xh,
            u16* __restrict__ Xl)
{
    int i = (blockIdx.x * 256 + threadIdx.x) * 8;
#pragma unroll
    for (int half = 0; half < 2; ++half) {
        float4 v = *(const float4*)(X + i + half * 4);
        ushort4 hi, lo;
        hi.x = f2bf(v.x); lo.x = f2bf(v.x - bf2f(hi.x));
        hi.y = f2bf(v.y); lo.y = f2bf(v.y - bf2f(hi.y));
        hi.z = f2bf(v.z); lo.z = f2bf(v.z - bf2f(hi.z));
        hi.w = f2bf(v.w); lo.w = f2bf(v.w - bf2f(hi.w));
        *(ushort4*)(Xh + i + half * 4) = hi;
        *(ushort4*)(Xl + i + half * 4) = lo;
    }
}

// ---------------------------------------------------------------------------
// Wq/Wk [16][1024][64] -> transposed hi/lo bf16 [h*64+d][e].  grid (32,16,2).
// ---------------------------------------------------------------------------
__global__ __launch_bounds__(256)
void wtrans(const float* __restrict__ Wq, const float* __restrict__ Wk,
            u16* __restrict__ Qth, u16* __restrict__ Qtl,
            u16* __restrict__ Kth, u16* __restrict__ Ktl)
{
    const float* W  = blockIdx.z ? Wk  : Wq;
    u16* Oh         = blockIdx.z ? Kth : Qth;
    u16* Ol         = blockIdx.z ? Ktl : Qtl;
    const int h  = blockIdx.y;
    const int d  = threadIdx.x & 63;
    const int e0 = (blockIdx.x * 4 + (threadIdx.x >> 6)) * 8;

    const float* src = W + ((size_t)h * EMB + e0) * HDIM + d;
    ushort4 h0, h1, l0, l1;
    float v; u16 hv;
    v = src[0 * 64]; hv = f2bf(v); h0.x = hv; l0.x = f2bf(v - bf2f(hv));
    v = src[1 * 64]; hv = f2bf(v); h0.y = hv; l0.y = f2bf(v - bf2f(hv));
    v = src[2 * 64]; hv = f2bf(v); h0.z = hv; l0.z = f2bf(v - bf2f(hv));
    v = src[3 * 64]; hv = f2bf(v); h0.w = hv; l0.w = f2bf(v - bf2f(hv));
    v = src[4 * 64]; hv = f2bf(v); h1.x = hv; l1.x = f2bf(v - bf2f(hv));
    v = src[5 * 64]; hv = f2bf(v); h1.y = hv; l1.y = f2bf(v - bf2f(hv));
    v = src[6 * 64]; hv = f2bf(v); h1.z = hv; l1.z = f2bf(v - bf2f(hv));
    v = src[7 * 64]; hv = f2bf(v); h1.w = hv; l1.w = f2bf(v - bf2f(hv));

    size_t obase = ((size_t)h * HDIM + d) * EMB + e0;
    *(ushort4*)(Oh + obase)     = h0;
    *(ushort4*)(Oh + obase + 4) = h1;
    *(ushort4*)(Ol + obase)     = l0;
    *(ushort4*)(Ol + obase + 4) = l1;
}

// ---------------------------------------------------------------------------
// Wv [16][1024][64] -> transposed bf16 (hi only) [h*64+d][e].  grid (32,16).
// ---------------------------------------------------------------------------
__global__ __launch_bounds__(256)
void wtrans_v(const float* __restrict__ Wv, u16* __restrict__ Vth)
{
    const int h  = blockIdx.y;
    const int d  = threadIdx.x & 63;
    const int e0 = (blockIdx.x * 4 + (threadIdx.x >> 6)) * 8;
    const float* src = Wv + ((size_t)h * EMB + e0) * HDIM + d;
    ushort4 h0, h1;
    h0.x = f2bf(src[0 * 64]); h0.y = f2bf(src[1 * 64]);
    h0.z = f2bf(src[2 * 64]); h0.w = f2bf(src[3 * 64]);
    h1.x = f2bf(src[4 * 64]); h1.y = f2bf(src[5 * 64]);
    h1.z = f2bf(src[6 * 64]); h1.w = f2bf(src[7 * 64]);
    size_t obase = ((size_t)h * HDIM + d) * EMB + e0;
    *(ushort4*)(Vth + obase)     = h0;
    *(ushort4*)(Vth + obase + 4) = h1;
}

// ---------------------------------------------------------------------------
// Wo -> bf16 elementwise.
// ---------------------------------------------------------------------------
__global__ __launch_bounds__(256)
void conv_bf16(const float* __restrict__ src, u16* __restrict__ dst)
{
    int i = (blockIdx.x * 256 + threadIdx.x) * 4;
    float4 v = *(const float4*)(src + i);
    ushort4 o;
    o.x = f2bf(v.x); o.y = f2bf(v.y); o.z = f2bf(v.z); o.w = f2bf(v.w);
    *(ushort4*)(dst + i) = o;
}

// ---------------------------------------------------------------------------
// Kernel 1a: Q/K projection, 3-pass split-bf16, software-pipelined.
// grid (32, 8, 2), block 256 = 2x2 waves, tile 128x128, BK=32.
// ---------------------------------------------------------------------------
__global__ __launch_bounds__(256)
void qkv_z01(const u16* __restrict__ Xh, const u16* __restrict__ Xl,
             const u16* __restrict__ Wqh, const u16* __restrict__ Wql,
             const u16* __restrict__ Wkh, const u16* __restrict__ Wkl,
             u16* __restrict__ Qh, u16* __restrict__ Ql,
             u16* __restrict__ Kh, u16* __restrict__ Kl)
{
    const int z  = blockIdx.z;
    const int m0 = blockIdx.x * 128;
    const int n0 = blockIdx.y * 128;
    const int t    = threadIdx.x;
    const int wave = t >> 6, lane = t & 63;
    const int wm = wave & 1, wn = wave >> 1;
    const int l16 = lane & 15, quad = lane >> 4;

    __shared__ u16 Ahs[128][STR];
    __shared__ u16 Als[128][STR];
    __shared__ u16 Bhs[128][STR];
    __shared__ u16 Bls[128][STR];

    const u16* Bh_g = z ? Wkh : Wqh;
    const u16* Bl_g = z ? Wkl : Wql;

    const int ar0 = t >> 2, ak = (t & 3) * 8, ar1 = ar0 + 64;

    f32x4 acc[4][4];
#pragma unroll
    for (int i = 0; i < 4; ++i)
#pragma unroll
        for (int j = 0; j < 4; ++j) acc[i][j] = (f32x4){0.f, 0.f, 0.f, 0.f};

    bf16x8 cur[8], nxt[8];
#define QK_LOAD(dst, kk)                                                        \
    do {                                                                        \
        dst[0] = *(const bf16x8*)(Xh  + (size_t)(m0 + ar0) * EMB + (kk) + ak);  \
        dst[1] = *(const bf16x8*)(Xh  + (size_t)(m0 + ar1) * EMB + (kk) + ak);  \
        dst[2] = *(const bf16x8*)(Xl  + (size_t)(m0 + ar0) * EMB + (kk) + ak);  \
        dst[3] = *(const bf16x8*)(Xl  + (size_t)(m0 + ar1) * EMB + (kk) + ak);  \
        dst[4] = *(const bf16x8*)(Bh_g + (size_t)(n0 + ar0) * EMB + (kk) + ak); \
        dst[5] = *(const bf16x8*)(Bh_g + (size_t)(n0 + ar1) * EMB + (kk) + ak); \
        dst[6] = *(const bf16x8*)(Bl_g + (size_t)(n0 + ar0) * EMB + (kk) + ak); \
        dst[7] = *(const bf16x8*)(Bl_g + (size_t)(n0 + ar1) * EMB + (kk) + ak); \
    } while (0)

    QK_LOAD(cur, 0);

    for (int k0 = 0; k0 < EMB; k0 += 32) {
        __syncthreads();
        *(bf16x8*)&Ahs[ar0][ak] = cur[0];  *(bf16x8*)&Ahs[ar1][ak] = cur[1];
        *(bf16x8*)&Als[ar0][ak] = cur[2];  *(bf16x8*)&Als[ar1][ak] = cur[3];
        *(bf16x8*)&Bhs[ar0][ak] = cur[4];  *(bf16x8*)&Bhs[ar1][ak] = cur[5];
        *(bf16x8*)&Bls[ar0][ak] = cur[6];  *(bf16x8*)&Bls[ar1][ak] = cur[7];
        __syncthreads();

        const int kn = (k0 + 32 < EMB) ? k0 + 32 : 0;   // dummy reload on last
        QK_LOAD(nxt, kn);

        bf16x8 B4h[4], B4l[4];
#pragma unroll
        for (int j = 0; j < 4; ++j) {
            B4h[j] = *(const bf16x8*)&Bhs[wn * 64 + 16 * j + l16][quad * 8];
            B4l[j] = *(const bf16x8*)&Bls[wn * 64 + 16 * j + l16][quad * 8];
        }
#pragma unroll
        for (int i = 0; i < 4; ++i) {
            bf16x8 Ai_h = *(const bf16x8*)&Ahs[wm * 64 + 16 * i + l16][quad * 8];
            bf16x8 Ai_l = *(const bf16x8*)&Als[wm * 64 + 16 * i + l16][quad * 8];
#pragma unroll
            for (int j = 0; j < 4; ++j) {
                acc[i][j] = __builtin_amdgcn_mfma_f32_16x16x32_bf16(Ai_h, B4h[j], acc[i][j], 0, 0, 0);
                acc[i][j] = __builtin_amdgcn_mfma_f32_16x16x32_bf16(Ai_h, B4l[j], acc[i][j], 0, 0, 0);
                acc[i][j] = __builtin_amdgcn_mfma_f32_16x16x32_bf16(Ai_l, B4h[j], acc[i][j], 0, 0, 0);
            }
        }
#pragma unroll
        for (int q = 0; q < 8; ++q) cur[q] = nxt[q];
    }
#undef QK_LOAD

    const int b = m0 >> 11;
    const int h = (n0 + wn * 64) >> 6;
    u16* Oh = z ? Kh : Qh;
    u16* Ol = z ? Kl : Ql;
#pragma unroll
    for (int i = 0; i < 4; ++i)
#pragma unroll
        for (int r = 0; r < 4; ++r) {
            int tt = (m0 & (SEQ - 1)) + wm * 64 + 16 * i + quad * 4 + r;
            size_t rowbase = ((size_t)(b * HEADS + h) * SEQ + tt) * HDIM;
#pragma unroll
            for (int j = 0; j < 4; ++j) {
                int d = 16 * j + l16;
                float v = acc[i][j][r];
                u16 hv = f2bf(v);
                Oh[rowbase + d] = hv;
                Ol[rowbase + d] = f2bf(v - bf2f(hv));
            }
        }
}

// ---------------------------------------------------------------------------
// Kernel 1b: V projection, 1-pass bf16, pipelined.  grid (32, 8), block 256.
// Epilogue writes Vt[bh][d][t] (transposed for attention's PV A-operand).
// ---------------------------------------------------------------------------
__global__ __launch_bounds__(256)
void qkv_v(const u16* __restrict__ Xh, const u16* __restrict__ Wvt,
           u16* __restrict__ Vt)
{
    const int m0 = blockIdx.x * 128;
    const int n0 = blockIdx.y * 128;
    const int t    = threadIdx.x;
    const int wave = t >> 6, lane = t & 63;
    const int wm = wave & 1, wn = wave >> 1;
    const int l16 = lane & 15, quad = lane >> 4;

    __shared__ u16 Ahs[128][STR];
    __shared__ u16 Bhs[128][STR];

    const int ar0 = t >> 2, ak = (t & 3) * 8, ar1 = ar0 + 64;

    f32x4 acc[4][4];
#pragma unroll
    for (int i = 0; i < 4; ++i)
#pragma unroll
        for (int j = 0; j < 4; ++j) acc[i][j] = (f32x4){0.f, 0.f, 0.f, 0.f};

    bf16x8 cur[4], nxt[4];
#define V_LOAD(dst, kk)                                                         \
    do {                                                                        \
        dst[0] = *(const bf16x8*)(Xh  + (size_t)(m0 + ar0) * EMB + (kk) + ak);  \
        dst[1] = *(const bf16x8*)(Xh  + (size_t)(m0 + ar1) * EMB + (kk) + ak);  \
        dst[2] = *(const bf16x8*)(Wvt + (size_t)(n0 + ar0) * EMB + (kk) + ak);  \
        dst[3] = *(const bf16x8*)(Wvt + (size_t)(n0 + ar1) * EMB + (kk) + ak);  \
    } while (0)

    V_LOAD(cur, 0);

    for (int k0 = 0; k0 < EMB; k0 += 32) {
        __syncthreads();
        *(bf16x8*)&Ahs[ar0][ak] = cur[0];  *(bf16x8*)&Ahs[ar1][ak] = cur[1];
        *(bf16x8*)&Bhs[ar0][ak] = cur[2];  *(bf16x8*)&Bhs[ar1][ak] = cur[3];
        __syncthreads();

        const int kn = (k0 + 32 < EMB) ? k0 + 32 : 0;
        V_LOAD(nxt, kn);

        bf16x8 B4[4];
#pragma unroll
        for (int j = 0; j < 4; ++j)
            B4[j] = *(const bf16x8*)&Bhs[wn * 64 + 16 * j + l16][quad * 8];
#pragma unroll
        for (int i = 0; i < 4; ++i) {
            bf16x8 Ai = *(const bf16x8*)&Ahs[wm * 64 + 16 * i + l16][quad * 8];
#pragma unroll
            for (int j = 0; j < 4; ++j)
                acc[i][j] = __builtin_amdgcn_mfma_f32_16x16x32_bf16(Ai, B4[j], acc[i][j], 0, 0, 0);
        }
#pragma unroll
        for (int q = 0; q < 4; ++q) cur[q] = nxt[q];
    }
#undef V_LOAD

    const int b = m0 >> 11;
    const int h = (n0 + wn * 64) >> 6;
#pragma unroll
    for (int i = 0; i < 4; ++i)
#pragma unroll
        for (int j = 0; j < 4; ++j) {
            int d  = 16 * j + l16;
            int tt = (m0 & (SEQ - 1)) + wm * 64 + 16 * i + quad * 4;
            ushort4 o;
            o.x = f2bf(acc[i][j][0]); o.y = f2bf(acc[i][j][1]);
            o.z = f2bf(acc[i][j][2]); o.w = f2bf(acc[i][j][3]);
            *(ushort4*)(Vt + ((size_t)(b * HEADS + h) * HDIM + d) * SEQ + tt) = o;
        }
}

// ---------------------------------------------------------------------------
// Kernel 2: flash attention, TRANSPOSED-score MFMA form.
// S^T = K Q^T  (A = K-tile from LDS, B = Q-frags in registers).
// C-layout: col = lane&15 = q  ->  each lane owns one q-row (16 s-values).
// Softmax: local 16-reduce + 2 shfl_xor (16,32); m/l/alpha are lane scalars.
// P^T write: 4x ushort4 (b64, floor-rate).  PV: O^T = V^T P^T; Vs already
// [d][s] (A-operand); P^T B-frag = lane's own row, b128, same-wave RAW.
// ---------------------------------------------------------------------------
__global__ __launch_bounds__(256)
void attn_mfma(const u16* __restrict__ Qh, const u16* __restrict__ Ql,
               const u16* __restrict__ Kh, const u16* __restrict__ Kl,
               const u16* __restrict__ Vt, u16* __restrict__ Cb)
{
    const int qt0  = blockIdx.x * 64;
    const int bh   = blockIdx.y;
    const int t    = threadIdx.x;
    const int wave = t >> 6;
    const int lane = t & 63;
    const int l16  = lane & 15;
    const int quad = lane >> 4;

    __shared__ u16 Ksh[64][72];   // K hi [s][d]
    __shared__ u16 Ksl[64][72];   // K lo [s][d]
    __shared__ u16 Vs [64][72];   // V^T  [d][s]
    __shared__ u16 Ps [64][72];   // P    [q][s]  (row = wave*16 + l16)

    const size_t bh_off = (size_t)bh * SEQ * HDIM;
    const u16* Qhb = Qh + bh_off;
    const u16* Qlb = Ql + bh_off;
    const u16* Khb = Kh + bh_off;
    const u16* Klb = Kl + bh_off;
    const u16* Vtb = Vt + bh_off;   // [64][SEQ]

    // Q fragments (B-operand: lane l16 = q, k = 32c + quad*8 + jj)
    bf16x8 aQh[2], aQl[2];
    {
        const int qrow = qt0 + wave * 16 + l16;
        const u16* bH = Qhb + (size_t)qrow * HDIM + quad * 8;
        const u16* bL = Qlb + (size_t)qrow * HDIM + quad * 8;
        aQh[0] = *(const bf16x8*)(bH);
        aQh[1] = *(const bf16x8*)(bH + 32);
        aQl[0] = *(const bf16x8*)(bL);
        aQl[1] = *(const bf16x8*)(bL + 32);
    }

    f32x4 accO[4];                 // O^T: [j = d-tile][reg = d%16 within quad]
    float m_i = -1e30f, l_i = 0.f; // lane scalars (q = this lane's row)
#pragma unroll
    for (int j = 0; j < 4; ++j) accO[j] = (f32x4){0.f, 0.f, 0.f, 0.f};

    const int r0 = t >> 3,          c0 = (t & 7) * 8;
    const int r1 = (t + 256) >> 3,  c1 = (t & 7) * 8;

    bf16x8 cur[6], nxt[6];
#define KV_LOAD(dst, ss)                                                       \
    do {                                                                       \
        dst[0] = *(const bf16x8*)(Khb + (size_t)((ss) + r0) * HDIM + c0);      \
        dst[1] = *(const bf16x8*)(Khb + (size_t)((ss) + r1) * HDIM + c1);      \
        dst[2] = *(const bf16x8*)(Klb + (size_t)((ss) + r0) * HDIM + c0);      \
        dst[3] = *(const bf16x8*)(Klb + (size_t)((ss) + r1) * HDIM + c1);      \
        dst[4] = *(const bf16x8*)(Vtb + (size_t)r0 * SEQ + (ss) + c0);         \
        dst[5] = *(const bf16x8*)(Vtb + (size_t)r1 * SEQ + (ss) + c1);         \
    } while (0)

    KV_LOAD(cur, 0);

    for (int s0 = 0; s0 < SEQ; s0 += 64) {
        __syncthreads();
        *(bf16x8*)&Ksh[r0][c0] = cur[0];  *(bf16x8*)&Ksh[r1][c1] = cur[1];
        *(bf16x8*)&Ksl[r0][c0] = cur[2];  *(bf16x8*)&Ksl[r1][c1] = cur[3];
        *(bf16x8*)&Vs [r0][c0] = cur[4];  *(bf16x8*)&Vs [r1][c1] = cur[5];
        __syncthreads();

        const int sn = (s0 + 64 < SEQ) ? s0 + 64 : 0;
        KV_LOAD(nxt, sn);

        // ---- S^T = K Q^T (3-pass split); accS[i] holds s = 16i+quad*4+r ----
        f32x4 accS[4];
#pragma unroll
        for (int i = 0; i < 4; ++i) accS[i] = (f32x4){0.f, 0.f, 0.f, 0.f};
#pragma unroll
        for (int c = 0; c < 2; ++c) {
#pragma unroll
            for (int i = 0; i < 4; ++i) {
                bf16x8 kh_ = *(const bf16x8*)&Ksh[16 * i + l16][c * 32 + quad * 8];
                bf16x8 kl_ = *(const bf16x8*)&Ksl[16 * i + l16][c * 32 + quad * 8];
                accS[i] = __builtin_amdgcn_mfma_f32_16x16x32_bf16(kh_, aQh[c], accS[i], 0, 0, 0);
                accS[i] = __builtin_amdgcn_mfma_f32_16x16x32_bf16(kl_, aQh[c], accS[i], 0, 0, 0);
                accS[i] = __builtin_amdgcn_mfma_f32_16x16x32_bf16(kh_, aQl[c], accS[i], 0, 0, 0);
            }
        }
#pragma unroll
        for (int i = 0; i < 4; ++i) accS[i] *= 0.125f;

        // ---- online softmax, per-lane (lane owns q-row l16) ----
        float vmax = fmaxf(fmaxf(accS[0][0], accS[0][1]), fmaxf(accS[0][2], accS[0][3]));
#pragma unroll
        for (int i = 1; i < 4; ++i)
            vmax = fmaxf(vmax, fmaxf(fmaxf(accS[i][0], accS[i][1]),
                                     fmaxf(accS[i][2], accS[i][3])));
        vmax = fmaxf(vmax, __shfl_xor(vmax, 16, 64));
        vmax = fmaxf(vmax, __shfl_xor(vmax, 32, 64));
        float mn   = fmaxf(m_i, vmax);
        float alph = __expf(m_i - mn);
        m_i = mn;
        float P[4][4], s = 0.f;
#pragma unroll
        for (int i = 0; i < 4; ++i)
#pragma unroll
            for (int r = 0; r < 4; ++r) {
                P[i][r] = __expf(accS[i][r] - mn);
                s += P[i][r];
            }
        s += __shfl_xor(s, 16, 64);
        s += __shfl_xor(s, 32, 64);
        l_i = l_i * alph + s;
#pragma unroll
        for (int j = 0; j < 4; ++j) accO[j] *= alph;

        // P^T -> LDS: lane writes its own q-row, 4 consecutive s per store
#pragma unroll
        for (int i = 0; i < 4; ++i) {
            ushort4 o;
            o.x = f2bf(P[i][0]); o.y = f2bf(P[i][1]);
            o.z = f2bf(P[i][2]); o.w = f2bf(P[i][3]);
            *(ushort4*)&Ps[wave * 16 + l16][16 * i + quad * 4] = o;
        }

        // ---- O^T += V^T P^T  (A = Vs[d][s], B = lane's own P-row) ----
#pragma unroll
        for (int c = 0; c < 2; ++c) {
            bf16x8 bP = *(const bf16x8*)&Ps[wave * 16 + l16][c * 32 + quad * 8];
#pragma unroll
            for (int j = 0; j < 4; ++j) {
                bf16x8 aV = *(const bf16x8*)&Vs[16 * j + l16][c * 32 + quad * 8];
                accO[j] = __builtin_amdgcn_mfma_f32_16x16x32_bf16(aV, bP, accO[j], 0, 0, 0);
            }
        }
#pragma unroll
        for (int q = 0; q < 6; ++q) cur[q] = nxt[q];
    }
#undef KV_LOAD

    // epilogue: O^T lane layout = 16 d-values of q-row l16; pack ushort4
    const int b = bh >> 4, h = bh & 15;
    const int row = qt0 + wave * 16 + l16;
    const float inv = 1.f / l_i;
#pragma unroll
    for (int j = 0; j < 4; ++j) {
        ushort4 o;
        o.x = f2bf(accO[j][0] * inv); o.y = f2bf(accO[j][1] * inv);
        o.z = f2bf(accO[j][2] * inv); o.w = f2bf(accO[j][3] * inv);
        *(ushort4*)&Cb[((size_t)b * SEQ + row) * EMB + h * HDIM + 16 * j + quad * 4] = o;
    }
}

// ---------------------------------------------------------------------------
// Kernel 3: Y = X + C @ Wo^T, bf16 MFMA, 128x128 tile, pipelined.
// grid (32, 8), block 256 = 2x2 waves.
// ---------------------------------------------------------------------------
__global__ __launch_bounds__(256)
void oproj_mfma(const u16* __restrict__ Cb, const u16* __restrict__ Woh,
                const float* __restrict__ X, float* __restrict__ Y)
{
    const int m0 = blockIdx.x * 128;
    const int n0 = blockIdx.y * 128;
    const int t    = threadIdx.x;
    const int wave = t >> 6, lane = t & 63;
    const int wm = wave & 1, wn = wave >> 1;
    const int l16 = lane & 15, quad = lane >> 4;

    __shared__ u16 Ahs[128][STR];
    __shared__ u16 Bhs[128][STR];

    const int ar0 = t >> 2, ak = (t & 3) * 8, ar1 = ar0 + 64;

    f32x4 acc[4][4];
#pragma unroll
    for (int i = 0; i < 4; ++i)
#pragma unroll
        for (int j = 0; j < 4; ++j) acc[i][j] = (f32x4){0.f, 0.f, 0.f, 0.f};

    bf16x8 cur[4], nxt[4];
#define O_LOAD(dst, kk)                                                         \
    do {                                                                        \
        dst[0] = *(const bf16x8*)(Cb  + (size_t)(m0 + ar0) * EMB + (kk) + ak);  \
        dst[1] = *(const bf16x8*)(Cb  + (size_t)(m0 + ar1) * EMB + (kk) + ak);  \
        dst[2] = *(const bf16x8*)(Woh + (size_t)(n0 + ar0) * EMB + (kk) + ak);  \
        dst[3] = *(const bf16x8*)(Woh + (size_t)(n0 + ar1) * EMB + (kk) + ak);  \
    } while (0)

    O_LOAD(cur, 0);

    for (int k0 = 0; k0 < EMB; k0 += 32) {
        __syncthreads();
        *(bf16x8*)&Ahs[ar0][ak] = cur[0];  *(bf16x8*)&Ahs[ar1][ak] = cur[1];
        *(bf16x8*)&Bhs[ar0][ak] = cur[2];  *(bf16x8*)&Bhs[ar1][ak] = cur[3];
        __syncthreads();

        const int kn = (k0 + 32 < EMB) ? k0 + 32 : 0;
        O_LOAD(nxt, kn);

        bf16x8 B4[4];
#pragma unroll
        for (int j = 0; j < 4; ++j)
            B4[j] = *(const bf16x8*)&Bhs[wn * 64 + 16 * j + l16][quad * 8];
#pragma unroll
        for (int i = 0; i < 4; ++i) {
            bf16x8 Ai = *(const bf16x8*)&Ahs[wm * 64 + 16 * i + l16][quad * 8];
#pragma unroll
            for (int j = 0; j < 4; ++j)
                acc[i][j] = __builtin_amdgcn_mfma_f32_16x16x32_bf16(Ai, B4[j], acc[i][j], 0, 0, 0);
        }
#pragma unroll
        for (int q = 0; q < 4; ++q) cur[q] = nxt[q];
    }
#undef O_LOAD

#pragma unroll
    for (int i = 0; i < 4; ++i)
#pragma unroll
        for (int r = 0; r < 4; ++r) {
            int m = m0 + wm * 64 + 16 * i + quad * 4 + r;
#pragma unroll
            for (int j = 0; j < 4; ++j) {
                int n = n0 + wn * 64 + 16 * j + l16;
                Y[(size_t)m * EMB + n] = acc[i][j][r] + X[(size_t)m * EMB + n];
            }
        }
}

// ---------------------------------------------------------------------------
// Workspace map (u16 units, 32M total = 64 MiB):
//   [0]   Qh 4M   [4M] Ql   [8M] Kh   [12M] Kl   [16M] Vt
//   [20M] Xh 4M   (-> Cb after qkv_v)
//   [24M] Xl 4M   (-> Woh after qkv_z01)
//   [28M] Wtq_h 1M (-> Wvt after qkv_z01), [29M] Wtq_l, [30M] Wtk_h, [31M] Wtk_l
// ---------------------------------------------------------------------------
extern "C" void kernel_launch(void* const* d_in, const int* in_sizes, int n_in,
                              void* d_out, int out_size, void* d_ws,
                              size_t ws_size, hipStream_t stream)
{
    const float* x  = (const float*)d_in[0];
    const float* Wq = (const float*)d_in[1];
    const float* Wk = (const float*)d_in[2];
    const float* Wv = (const float*)d_in[3];
    const float* Wo = (const float*)d_in[4];
    float* Y = (float*)d_out;

    const size_t NPER = (size_t)MROWS * EMB;   // 4,194,304
    u16* base  = (u16*)d_ws;
    u16* Qh    = base;
    u16* Ql    = Qh + NPER;
    u16* Kh    = Ql + NPER;
    u16* Kl    = Kh + NPER;
    u16* Vt    = Kl + NPER;
    u16* Xh    = Vt + NPER;
    u16* Xl    = Xh + NPER;
    u16* Wtq_h = Xl + NPER;
    u16* Wtq_l = Wtq_h + EMB * EMB;
    u16* Wtk_h = Wtq_l + EMB * EMB;
    u16* Wtk_l = Wtk_h + EMB * EMB;
    u16* Wvt   = Wtq_h;   // alias: Wtq dead after qkv_z01
    u16* Cb    = Xh;      // alias: Xh dead after qkv_v
    u16* Woh   = Xl;      // alias: Xl dead after qkv_z01

    xsplit<<<dim3(NPER / 2048), 256, 0, stream>>>(x, Xh, Xl);
    wtrans<<<dim3(32, 16, 2), 256, 0, stream>>>(Wq, Wk, Wtq_h, Wtq_l,
                                                Wtk_h, Wtk_l);
    qkv_z01<<<dim3(32, 8, 2), 256, 0, stream>>>(Xh, Xl, Wtq_h, Wtq_l,
                                                Wtk_h, Wtk_l, Qh, Ql, Kh, Kl);
    wtrans_v<<<dim3(32, 16), 256, 0, stream>>>(Wv, Wvt);
    conv_bf16<<<dim3(EMB * EMB / 1024), 256, 0, stream>>>(Wo, Woh);
    qkv_v<<<dim3(32, 8), 256, 0, stream>>>(Xh, Wvt, Vt);
    attn_mfma<<<dim3(SEQ / 64, BATCH * HEADS), 256, 0, stream>>>(Qh, Ql, Kh, Kl,
                                                                 Vt, Cb);
    oproj_mfma<<<dim3(32, 8), 256, 0, stream>>>(Cb, Woh, x, Y);
}

// Round 6
// 287.091 us; speedup vs baseline: 3.7919x; 1.0376x over previous
//
#include <hip/hip_runtime.h>

#define EMB   1024
#define HEADS 16
#define HDIM  64
#define BATCH 2
#define SEQ   2048
#define MROWS (BATCH*SEQ)   // 4096
#define STR   40            // qkv/oproj LDS k-stride in u16: 80 B
#define QSCALE 0.1803368801111204f   // 0.125 * log2(e): Q pre-scale -> exp2 softmax

typedef __attribute__((ext_vector_type(8))) short bf16x8;   // 8 bf16 (4 VGPRs)
typedef __attribute__((ext_vector_type(4))) float f32x4;    // MFMA C/D
typedef unsigned short u16;

__device__ __forceinline__ u16 f2bf(float f) {              // round-to-nearest-even
    unsigned u = __float_as_uint(f);
    u += 0x7fffu + ((u >> 16) & 1u);
    return (u16)(u >> 16);
}
__device__ __forceinline__ float bf2f(u16 h) {
    return __uint_as_float((unsigned)h << 16);
}
__device__ __forceinline__ float fast_exp2(float x) {
#if __has_builtin(__builtin_amdgcn_exp2f)
    return __builtin_amdgcn_exp2f(x);
#else
    return __expf(x * 0.6931471805599453f);
#endif
}
// pack two floats -> two truncated bf16 in one v_perm_b32 (lo in [15:0])
__device__ __forceinline__ unsigned pk_trunc(float lo, float hi) {
    return __builtin_amdgcn_perm(__float_as_uint(hi), __float_as_uint(lo),
                                 0x07060302u);
}

// XOR-swizzled LDS offset (u16 units): 64-u16 rows, 8-u16 chunks, chunk^=row&7.
// Makes every b128 access pattern in attn hit 8 distinct bank-quads per phase.
#define SWZ(r, ch) ((((r) << 6)) + ((((ch) ^ ((r) & 7))) << 3))

// ---------------------------------------------------------------------------
// prep1: fused  [bx<2048] X->Xh/Xl split  |  [else] Wq/Wk transpose+hi/lo.
// ---------------------------------------------------------------------------
__global__ __launch_bounds__(256)
void prep1(const float* __restrict__ X, const float* __restrict__ Wq,
           const float* __restrict__ Wk,
           u16* __restrict__ Xh, u16* __restrict__ Xl,
           u16* __restrict__ Qth, u16* __restrict__ Qtl,
           u16* __restrict__ Kth, u16* __restrict__ Ktl)
{
    const int bx = blockIdx.x;
    if (bx < 2048) {                       // xsplit: 8 elems/thread
        int i = (bx * 256 + threadIdx.x) * 8;
#pragma unroll
        for (int half = 0; half < 2; ++half) {
            float4 v = *(const float4*)(X + i + half * 4);
            ushort4 hi, lo;
            hi.x = f2bf(v.x); lo.x = f2bf(v.x - bf2f(hi.x));
            hi.y = f2bf(v.y); lo.y = f2bf(v.y - bf2f(hi.y));
            hi.z = f2bf(v.z); lo.z = f2bf(v.z - bf2f(hi.z));
            hi.w = f2bf(v.w); lo.w = f2bf(v.w - bf2f(hi.w));
            *(ushort4*)(Xh + i + half * 4) = hi;
            *(ushort4*)(Xl + i + half * 4) = lo;
        }
    } else {                               // wtrans: [16][1024][64] -> [h*64+d][e]
        const int f = bx - 2048;           // 0..1023
        const int z = f >> 9, y = (f >> 5) & 15, x = f & 31;
        const float* W  = z ? Wk  : Wq;
        u16* Oh         = z ? Kth : Qth;
        u16* Ol         = z ? Ktl : Qtl;
        const int d  = threadIdx.x & 63;
        const int e0 = (x * 4 + (threadIdx.x >> 6)) * 8;
        const float* src = W + ((size_t)y * EMB + e0) * HDIM + d;
        ushort4 h0, h1, l0, l1;
        float v; u16 hv;
        v = src[0 * 64]; hv = f2bf(v); h0.x = hv; l0.x = f2bf(v - bf2f(hv));
        v = src[1 * 64]; hv = f2bf(v); h0.y = hv; l0.y = f2bf(v - bf2f(hv));
        v = src[2 * 64]; hv = f2bf(v); h0.z = hv; l0.z = f2bf(v - bf2f(hv));
        v = src[3 * 64]; hv = f2bf(v); h0.w = hv; l0.w = f2bf(v - bf2f(hv));
        v = src[4 * 64]; hv = f2bf(v); h1.x = hv; l1.x = f2bf(v - bf2f(hv));
        v = src[5 * 64]; hv = f2bf(v); h1.y = hv; l1.y = f2bf(v - bf2f(hv));
        v = src[6 * 64]; hv = f2bf(v); h1.z = hv; l1.z = f2bf(v - bf2f(hv));
        v = src[7 * 64]; hv = f2bf(v); h1.w = hv; l1.w = f2bf(v - bf2f(hv));
        size_t obase = ((size_t)y * HDIM + d) * EMB + e0;
        *(ushort4*)(Oh + obase)     = h0;
        *(ushort4*)(Oh + obase + 4) = h1;
        *(ushort4*)(Ol + obase)     = l0;
        *(ushort4*)(Ol + obase + 4) = l1;
    }
}

// ---------------------------------------------------------------------------
// prep2 (after qkv_z01; Wvt aliases Wtq_h, Woh aliases Xl — both dead then):
// [f<512] Wv transpose->bf16  |  [else] Wo -> bf16.
// ---------------------------------------------------------------------------
__global__ __launch_bounds__(256)
void prep2(const float* __restrict__ Wv, const float* __restrict__ Wo,
           u16* __restrict__ Vth, u16* __restrict__ Woh)
{
    const int f = blockIdx.x;
    if (f < 512) {
        const int y = f >> 5, x = f & 31;
        const int d  = threadIdx.x & 63;
        const int e0 = (x * 4 + (threadIdx.x >> 6)) * 8;
        const float* src = Wv + ((size_t)y * EMB + e0) * HDIM + d;
        ushort4 h0, h1;
        h0.x = f2bf(src[0 * 64]); h0.y = f2bf(src[1 * 64]);
        h0.z = f2bf(src[2 * 64]); h0.w = f2bf(src[3 * 64]);
        h1.x = f2bf(src[4 * 64]); h1.y = f2bf(src[5 * 64]);
        h1.z = f2bf(src[6 * 64]); h1.w = f2bf(src[7 * 64]);
        size_t obase = ((size_t)y * HDIM + d) * EMB + e0;
        *(ushort4*)(Vth + obase)     = h0;
        *(ushort4*)(Vth + obase + 4) = h1;
    } else {
        int i = ((f - 512) * 256 + threadIdx.x) * 8;
#pragma unroll
        for (int half = 0; half < 2; ++half) {
            float4 v = *(const float4*)(Wo + i + half * 4);
            ushort4 o;
            o.x = f2bf(v.x); o.y = f2bf(v.y); o.z = f2bf(v.z); o.w = f2bf(v.w);
            *(ushort4*)(Woh + i + half * 4) = o;
        }
    }
}

// ---------------------------------------------------------------------------
// Kernel 1a: Q/K projection, 3-pass split-bf16, pipelined.  Q pre-scaled by
// QSCALE in the epilogue (softmax runs in log2 domain).
// ---------------------------------------------------------------------------
__global__ __launch_bounds__(256)
void qkv_z01(const u16* __restrict__ Xh, const u16* __restrict__ Xl,
             const u16* __restrict__ Wqh, const u16* __restrict__ Wql,
             const u16* __restrict__ Wkh, const u16* __restrict__ Wkl,
             u16* __restrict__ Qh, u16* __restrict__ Ql,
             u16* __restrict__ Kh, u16* __restrict__ Kl)
{
    const int z  = blockIdx.z;
    const int m0 = blockIdx.x * 128;
    const int n0 = blockIdx.y * 128;
    const int t    = threadIdx.x;
    const int wave = t >> 6, lane = t & 63;
    const int wm = wave & 1, wn = wave >> 1;
    const int l16 = lane & 15, quad = lane >> 4;

    __shared__ u16 Ahs[128][STR];
    __shared__ u16 Als[128][STR];
    __shared__ u16 Bhs[128][STR];
    __shared__ u16 Bls[128][STR];

    const u16* Bh_g = z ? Wkh : Wqh;
    const u16* Bl_g = z ? Wkl : Wql;

    const int ar0 = t >> 2, ak = (t & 3) * 8, ar1 = ar0 + 64;

    f32x4 acc[4][4];
#pragma unroll
    for (int i = 0; i < 4; ++i)
#pragma unroll
        for (int j = 0; j < 4; ++j) acc[i][j] = (f32x4){0.f, 0.f, 0.f, 0.f};

    bf16x8 cur[8], nxt[8];
#define QK_LOAD(dst, kk)                                                        \
    do {                                                                        \
        dst[0] = *(const bf16x8*)(Xh  + (size_t)(m0 + ar0) * EMB + (kk) + ak);  \
        dst[1] = *(const bf16x8*)(Xh  + (size_t)(m0 + ar1) * EMB + (kk) + ak);  \
        dst[2] = *(const bf16x8*)(Xl  + (size_t)(m0 + ar0) * EMB + (kk) + ak);  \
        dst[3] = *(const bf16x8*)(Xl  + (size_t)(m0 + ar1) * EMB + (kk) + ak);  \
        dst[4] = *(const bf16x8*)(Bh_g + (size_t)(n0 + ar0) * EMB + (kk) + ak); \
        dst[5] = *(const bf16x8*)(Bh_g + (size_t)(n0 + ar1) * EMB + (kk) + ak); \
        dst[6] = *(const bf16x8*)(Bl_g + (size_t)(n0 + ar0) * EMB + (kk) + ak); \
        dst[7] = *(const bf16x8*)(Bl_g + (size_t)(n0 + ar1) * EMB + (kk) + ak); \
    } while (0)

    QK_LOAD(cur, 0);

    for (int k0 = 0; k0 < EMB; k0 += 32) {
        __syncthreads();
        *(bf16x8*)&Ahs[ar0][ak] = cur[0];  *(bf16x8*)&Ahs[ar1][ak] = cur[1];
        *(bf16x8*)&Als[ar0][ak] = cur[2];  *(bf16x8*)&Als[ar1][ak] = cur[3];
        *(bf16x8*)&Bhs[ar0][ak] = cur[4];  *(bf16x8*)&Bhs[ar1][ak] = cur[5];
        *(bf16x8*)&Bls[ar0][ak] = cur[6];  *(bf16x8*)&Bls[ar1][ak] = cur[7];
        __syncthreads();

        const int kn = (k0 + 32 < EMB) ? k0 + 32 : 0;
        QK_LOAD(nxt, kn);

        bf16x8 B4h[4], B4l[4];
#pragma unroll
        for (int j = 0; j < 4; ++j) {
            B4h[j] = *(const bf16x8*)&Bhs[wn * 64 + 16 * j + l16][quad * 8];
            B4l[j] = *(const bf16x8*)&Bls[wn * 64 + 16 * j + l16][quad * 8];
        }
#pragma unroll
        for (int i = 0; i < 4; ++i) {
            bf16x8 Ai_h = *(const bf16x8*)&Ahs[wm * 64 + 16 * i + l16][quad * 8];
            bf16x8 Ai_l = *(const bf16x8*)&Als[wm * 64 + 16 * i + l16][quad * 8];
#pragma unroll
            for (int j = 0; j < 4; ++j) {
                acc[i][j] = __builtin_amdgcn_mfma_f32_16x16x32_bf16(Ai_h, B4h[j], acc[i][j], 0, 0, 0);
                acc[i][j] = __builtin_amdgcn_mfma_f32_16x16x32_bf16(Ai_h, B4l[j], acc[i][j], 0, 0, 0);
                acc[i][j] = __builtin_amdgcn_mfma_f32_16x16x32_bf16(Ai_l, B4h[j], acc[i][j], 0, 0, 0);
            }
        }
#pragma unroll
        for (int q = 0; q < 8; ++q) cur[q] = nxt[q];
    }
#undef QK_LOAD

    const int b = m0 >> 11;
    const int h = (n0 + wn * 64) >> 6;
    u16* Oh = z ? Kh : Qh;
    u16* Ol = z ? Kl : Ql;
    const float esc = z ? 1.0f : QSCALE;    // Q carries the softmax scale
#pragma unroll
    for (int i = 0; i < 4; ++i)
#pragma unroll
        for (int r = 0; r < 4; ++r) {
            int tt = (m0 & (SEQ - 1)) + wm * 64 + 16 * i + quad * 4 + r;
            size_t rowbase = ((size_t)(b * HEADS + h) * SEQ + tt) * HDIM;
#pragma unroll
            for (int j = 0; j < 4; ++j) {
                int d = 16 * j + l16;
                float v = acc[i][j][r] * esc;
                u16 hv = f2bf(v);
                Oh[rowbase + d] = hv;
                Ol[rowbase + d] = f2bf(v - bf2f(hv));
            }
        }
}

// ---------------------------------------------------------------------------
// Kernel 1b: V projection, 1-pass bf16, pipelined.  Writes Vt[bh][d][t].
// ---------------------------------------------------------------------------
__global__ __launch_bounds__(256)
void qkv_v(const u16* __restrict__ Xh, const u16* __restrict__ Wvt,
           u16* __restrict__ Vt)
{
    const int m0 = blockIdx.x * 128;
    const int n0 = blockIdx.y * 128;
    const int t    = threadIdx.x;
    const int wave = t >> 6, lane = t & 63;
    const int wm = wave & 1, wn = wave >> 1;
    const int l16 = lane & 15, quad = lane >> 4;

    __shared__ u16 Ahs[128][STR];
    __shared__ u16 Bhs[128][STR];

    const int ar0 = t >> 2, ak = (t & 3) * 8, ar1 = ar0 + 64;

    f32x4 acc[4][4];
#pragma unroll
    for (int i = 0; i < 4; ++i)
#pragma unroll
        for (int j = 0; j < 4; ++j) acc[i][j] = (f32x4){0.f, 0.f, 0.f, 0.f};

    bf16x8 cur[4], nxt[4];
#define V_LOAD(dst, kk)                                                         \
    do {                                                                        \
        dst[0] = *(const bf16x8*)(Xh  + (size_t)(m0 + ar0) * EMB + (kk) + ak);  \
        dst[1] = *(const bf16x8*)(Xh  + (size_t)(m0 + ar1) * EMB + (kk) + ak);  \
        dst[2] = *(const bf16x8*)(Wvt + (size_t)(n0 + ar0) * EMB + (kk) + ak);  \
        dst[3] = *(const bf16x8*)(Wvt + (size_t)(n0 + ar1) * EMB + (kk) + ak);  \
    } while (0)

    V_LOAD(cur, 0);

    for (int k0 = 0; k0 < EMB; k0 += 32) {
        __syncthreads();
        *(bf16x8*)&Ahs[ar0][ak] = cur[0];  *(bf16x8*)&Ahs[ar1][ak] = cur[1];
        *(bf16x8*)&Bhs[ar0][ak] = cur[2];  *(bf16x8*)&Bhs[ar1][ak] = cur[3];
        __syncthreads();

        const int kn = (k0 + 32 < EMB) ? k0 + 32 : 0;
        V_LOAD(nxt, kn);

        bf16x8 B4[4];
#pragma unroll
        for (int j = 0; j < 4; ++j)
            B4[j] = *(const bf16x8*)&Bhs[wn * 64 + 16 * j + l16][quad * 8];
#pragma unroll
        for (int i = 0; i < 4; ++i) {
            bf16x8 Ai = *(const bf16x8*)&Ahs[wm * 64 + 16 * i + l16][quad * 8];
#pragma unroll
            for (int j = 0; j < 4; ++j)
                acc[i][j] = __builtin_amdgcn_mfma_f32_16x16x32_bf16(Ai, B4[j], acc[i][j], 0, 0, 0);
        }
#pragma unroll
        for (int q = 0; q < 4; ++q) cur[q] = nxt[q];
    }
#undef V_LOAD

    const int b = m0 >> 11;
    const int h = (n0 + wn * 64) >> 6;
#pragma unroll
    for (int i = 0; i < 4; ++i)
#pragma unroll
        for (int j = 0; j < 4; ++j) {
            int d  = 16 * j + l16;
            int tt = (m0 & (SEQ - 1)) + wm * 64 + 16 * i + quad * 4;
            ushort4 o;
            o.x = f2bf(acc[i][j][0]); o.y = f2bf(acc[i][j][1]);
            o.z = f2bf(acc[i][j][2]); o.w = f2bf(acc[i][j][3]);
            *(ushort4*)(Vt + ((size_t)(b * HEADS + h) * HDIM + d) * SEQ + tt) = o;
        }
}

// ---------------------------------------------------------------------------
// Kernel 2: flash attention, transposed-score MFMA, XOR-swizzled LDS,
// log2-domain softmax (Q pre-scaled by QSCALE), v_perm P-packing.
// ---------------------------------------------------------------------------
__global__ __launch_bounds__(256)
void attn_mfma(const u16* __restrict__ Qh, const u16* __restrict__ Ql,
               const u16* __restrict__ Kh, const u16* __restrict__ Kl,
               const u16* __restrict__ Vt, u16* __restrict__ Cb)
{
    const int qt0  = blockIdx.x * 64;
    const int bh   = blockIdx.y;
    const int t    = threadIdx.x;
    const int wave = t >> 6;
    const int lane = t & 63;
    const int l16  = lane & 15;
    const int quad = lane >> 4;

    __shared__ u16 Ksh[4096];   // K hi [s][d], swizzled
    __shared__ u16 Ksl[4096];   // K lo [s][d], swizzled
    __shared__ u16 Vs [4096];   // V^T  [d][s], swizzled
    __shared__ u16 Ps [4096];   // P    [q][s], swizzled

    const size_t bh_off = (size_t)bh * SEQ * HDIM;
    const u16* Qhb = Qh + bh_off;
    const u16* Qlb = Ql + bh_off;
    const u16* Khb = Kh + bh_off;
    const u16* Klb = Kl + bh_off;
    const u16* Vtb = Vt + bh_off;   // [64][SEQ]

    bf16x8 aQh[2], aQl[2];
    {
        const int qrow = qt0 + wave * 16 + l16;
        const u16* bH = Qhb + (size_t)qrow * HDIM + quad * 8;
        const u16* bL = Qlb + (size_t)qrow * HDIM + quad * 8;
        aQh[0] = *(const bf16x8*)(bH);
        aQh[1] = *(const bf16x8*)(bH + 32);
        aQl[0] = *(const bf16x8*)(bL);
        aQl[1] = *(const bf16x8*)(bL + 32);
    }

    f32x4 accO[4];
    float m_i = -1e30f, l_i = 0.f;   // log2-domain running max, linear sum
#pragma unroll
    for (int j = 0; j < 4; ++j) accO[j] = (f32x4){0.f, 0.f, 0.f, 0.f};

    const int sr0 = t >> 3, sch = t & 7, sr1 = sr0 + 32;
    const int gc  = sch * 8;
    const int so0 = SWZ(sr0, sch), so1 = SWZ(sr1, sch);

    bf16x8 cur[6], nxt[6];
#define KV_LOAD(dst, ss)                                                       \
    do {                                                                       \
        dst[0] = *(const bf16x8*)(Khb + (size_t)((ss) + sr0) * HDIM + gc);     \
        dst[1] = *(const bf16x8*)(Khb + (size_t)((ss) + sr1) * HDIM + gc);     \
        dst[2] = *(const bf16x8*)(Klb + (size_t)((ss) + sr0) * HDIM + gc);     \
        dst[3] = *(const bf16x8*)(Klb + (size_t)((ss) + sr1) * HDIM + gc);     \
        dst[4] = *(const bf16x8*)(Vtb + (size_t)sr0 * SEQ + (ss) + gc);        \
        dst[5] = *(const bf16x8*)(Vtb + (size_t)sr1 * SEQ + (ss) + gc);        \
    } while (0)

    KV_LOAD(cur, 0);

    for (int s0 = 0; s0 < SEQ; s0 += 64) {
        __syncthreads();
        *(bf16x8*)&Ksh[so0] = cur[0];  *(bf16x8*)&Ksh[so1] = cur[1];
        *(bf16x8*)&Ksl[so0] = cur[2];  *(bf16x8*)&Ksl[so1] = cur[3];
        *(bf16x8*)&Vs [so0] = cur[4];  *(bf16x8*)&Vs [so1] = cur[5];
        __syncthreads();

        const int sn = (s0 + 64 < SEQ) ? s0 + 64 : 0;
        KV_LOAD(nxt, sn);

        // ---- S^T = K Q^T (3-pass split), already in log2 domain ----
        f32x4 accS[4];
#pragma unroll
        for (int i = 0; i < 4; ++i) accS[i] = (f32x4){0.f, 0.f, 0.f, 0.f};
#pragma unroll
        for (int c = 0; c < 2; ++c) {
#pragma unroll
            for (int i = 0; i < 4; ++i) {
                bf16x8 kh_ = *(const bf16x8*)&Ksh[SWZ(16 * i + l16, 4 * c + quad)];
                bf16x8 kl_ = *(const bf16x8*)&Ksl[SWZ(16 * i + l16, 4 * c + quad)];
                accS[i] = __builtin_amdgcn_mfma_f32_16x16x32_bf16(kh_, aQh[c], accS[i], 0, 0, 0);
                accS[i] = __builtin_amdgcn_mfma_f32_16x16x32_bf16(kl_, aQh[c], accS[i], 0, 0, 0);
                accS[i] = __builtin_amdgcn_mfma_f32_16x16x32_bf16(kh_, aQl[c], accS[i], 0, 0, 0);
            }
        }

        // ---- online softmax (per-lane; lane owns q-row l16) ----
        float vmax = fmaxf(fmaxf(accS[0][0], accS[0][1]), fmaxf(accS[0][2], accS[0][3]));
#pragma unroll
        for (int i = 1; i < 4; ++i)
            vmax = fmaxf(vmax, fmaxf(fmaxf(accS[i][0], accS[i][1]),
                                     fmaxf(accS[i][2], accS[i][3])));
        vmax = fmaxf(vmax, __shfl_xor(vmax, 16, 64));
        vmax = fmaxf(vmax, __shfl_xor(vmax, 32, 64));
        float mn   = fmaxf(m_i, vmax);
        float alph = fast_exp2(m_i - mn);
        m_i = mn;
        float P[4][4], s = 0.f;
#pragma unroll
        for (int i = 0; i < 4; ++i)
#pragma unroll
            for (int r = 0; r < 4; ++r) {
                P[i][r] = fast_exp2(accS[i][r] - mn);
                s += P[i][r];
            }
        s += __shfl_xor(s, 16, 64);
        s += __shfl_xor(s, 32, 64);
        l_i = l_i * alph + s;
#pragma unroll
        for (int j = 0; j < 4; ++j) accO[j] *= alph;

        // P^T -> LDS (truncating bf16 via v_perm; lane's own row; b64 stores)
        const int prow = wave * 16 + l16;
#pragma unroll
        for (int i = 0; i < 4; ++i) {
            uint2 pv;
            pv.x = pk_trunc(P[i][0], P[i][1]);
            pv.y = pk_trunc(P[i][2], P[i][3]);
            *(uint2*)&Ps[SWZ(prow, 2 * i + (quad >> 1)) + ((quad & 1) << 2)] = pv;
        }

        // ---- O^T += V^T P^T ----
#pragma unroll
        for (int c = 0; c < 2; ++c) {
            bf16x8 bP = *(const bf16x8*)&Ps[SWZ(prow, 4 * c + quad)];
#pragma unroll
            for (int j = 0; j < 4; ++j) {
                bf16x8 aV = *(const bf16x8*)&Vs[SWZ(16 * j + l16, 4 * c + quad)];
                accO[j] = __builtin_amdgcn_mfma_f32_16x16x32_bf16(aV, bP, accO[j], 0, 0, 0);
            }
        }
#pragma unroll
        for (int q = 0; q < 6; ++q) cur[q] = nxt[q];
    }
#undef KV_LOAD

    const int b = bh >> 4, h = bh & 15;
    const int row = qt0 + wave * 16 + l16;
    const float inv = 1.f / l_i;
#pragma unroll
    for (int j = 0; j < 4; ++j) {
        ushort4 o;
        o.x = f2bf(accO[j][0] * inv); o.y = f2bf(accO[j][1] * inv);
        o.z = f2bf(accO[j][2] * inv); o.w = f2bf(accO[j][3] * inv);
        *(ushort4*)&Cb[((size_t)b * SEQ + row) * EMB + h * HDIM + 16 * j + quad * 4] = o;
    }
}

// ---------------------------------------------------------------------------
// Kernel 3: Y = X + C @ Wo^T, bf16 MFMA, 128x128, pipelined.
// ---------------------------------------------------------------------------
__global__ __launch_bounds__(256)
void oproj_mfma(const u16* __restrict__ Cb, const u16* __restrict__ Woh,
                const float* __restrict__ X, float* __restrict__ Y)
{
    const int m0 = blockIdx.x * 128;
    const int n0 = blockIdx.y * 128;
    const int t    = threadIdx.x;
    const int wave = t >> 6, lane = t & 63;
    const int wm = wave & 1, wn = wave >> 1;
    const int l16 = lane & 15, quad = lane >> 4;

    __shared__ u16 Ahs[128][STR];
    __shared__ u16 Bhs[128][STR];

    const int ar0 = t >> 2, ak = (t & 3) * 8, ar1 = ar0 + 64;

    f32x4 acc[4][4];
#pragma unroll
    for (int i = 0; i < 4; ++i)
#pragma unroll
        for (int j = 0; j < 4; ++j) acc[i][j] = (f32x4){0.f, 0.f, 0.f, 0.f};

    bf16x8 cur[4], nxt[4];
#define O_LOAD(dst, kk)                                                         \
    do {                                                                        \
        dst[0] = *(const bf16x8*)(Cb  + (size_t)(m0 + ar0) * EMB + (kk) + ak);  \
        dst[1] = *(const bf16x8*)(Cb  + (size_t)(m0 + ar1) * EMB + (kk) + ak);  \
        dst[2] = *(const bf16x8*)(Woh + (size_t)(n0 + ar0) * EMB + (kk) + ak);  \
        dst[3] = *(const bf16x8*)(Woh + (size_t)(n0 + ar1) * EMB + (kk) + ak);  \
    } while (0)

    O_LOAD(cur, 0);

    for (int k0 = 0; k0 < EMB; k0 += 32) {
        __syncthreads();
        *(bf16x8*)&Ahs[ar0][ak] = cur[0];  *(bf16x8*)&Ahs[ar1][ak] = cur[1];
        *(bf16x8*)&Bhs[ar0][ak] = cur[2];  *(bf16x8*)&Bhs[ar1][ak] = cur[3];
        __syncthreads();

        const int kn = (k0 + 32 < EMB) ? k0 + 32 : 0;
        O_LOAD(nxt, kn);

        bf16x8 B4[4];
#pragma unroll
        for (int j = 0; j < 4; ++j)
            B4[j] = *(const bf16x8*)&Bhs[wn * 64 + 16 * j + l16][quad * 8];
#pragma unroll
        for (int i = 0; i < 4; ++i) {
            bf16x8 Ai = *(const bf16x8*)&Ahs[wm * 64 + 16 * i + l16][quad * 8];
#pragma unroll
            for (int j = 0; j < 4; ++j)
                acc[i][j] = __builtin_amdgcn_mfma_f32_16x16x32_bf16(Ai, B4[j], acc[i][j], 0, 0, 0);
        }
#pragma unroll
        for (int q = 0; q < 4; ++q) cur[q] = nxt[q];
    }
#undef O_LOAD

#pragma unroll
    for (int i = 0; i < 4; ++i)
#pragma unroll
        for (int r = 0; r < 4; ++r) {
            int m = m0 + wm * 64 + 16 * i + quad * 4 + r;
#pragma unroll
            for (int j = 0; j < 4; ++j) {
                int n = n0 + wn * 64 + 16 * j + l16;
                Y[(size_t)m * EMB + n] = acc[i][j][r] + X[(size_t)m * EMB + n];
            }
        }
}

// ---------------------------------------------------------------------------
// Workspace map (u16 units, 32M total = 64 MiB):
//   [0]   Qh 4M   [4M] Ql   [8M] Kh   [12M] Kl   [16M] Vt
//   [20M] Xh 4M   (-> Cb after qkv_v)
//   [24M] Xl 4M   (-> Woh after qkv_z01, written by prep2)
//   [28M] Wtq_h 1M (-> Wvt after qkv_z01, written by prep2), Wtq_l, Wtk_h, Wtk_l
// ---------------------------------------------------------------------------
extern "C" void kernel_launch(void* const* d_in, const int* in_sizes, int n_in,
                              void* d_out, int out_size, void* d_ws,
                              size_t ws_size, hipStream_t stream)
{
    const float* x  = (const float*)d_in[0];
    const float* Wq = (const float*)d_in[1];
    const float* Wk = (const float*)d_in[2];
    const float* Wv = (const float*)d_in[3];
    const float* Wo = (const float*)d_in[4];
    float* Y = (float*)d_out;

    const size_t NPER = (size_t)MROWS * EMB;   // 4,194,304
    u16* base  = (u16*)d_ws;
    u16* Qh    = base;
    u16* Ql    = Qh + NPER;
    u16* Kh    = Ql + NPER;
    u16* Kl    = Kh + NPER;
    u16* Vt    = Kl + NPER;
    u16* Xh    = Vt + NPER;
    u16* Xl    = Xh + NPER;
    u16* Wtq_h = Xl + NPER;
    u16* Wtq_l = Wtq_h + EMB * EMB;
    u16* Wtk_h = Wtq_l + EMB * EMB;
    u16* Wtk_l = Wtk_h + EMB * EMB;
    u16* Wvt   = Wtq_h;   // alias: Wtq dead after qkv_z01
    u16* Cb    = Xh;      // alias: Xh dead after qkv_v
    u16* Woh   = Xl;      // alias: Xl dead after qkv_z01

    prep1<<<dim3(3072), 256, 0, stream>>>(x, Wq, Wk, Xh, Xl,
                                          Wtq_h, Wtq_l, Wtk_h, Wtk_l);
    qkv_z01<<<dim3(32, 8, 2), 256, 0, stream>>>(Xh, Xl, Wtq_h, Wtq_l,
                                                Wtk_h, Wtk_l, Qh, Ql, Kh, Kl);
    prep2<<<dim3(1024), 256, 0, stream>>>(Wv, Wo, Wvt, Woh);
    qkv_v<<<dim3(32, 8), 256, 0, stream>>>(Xh, Wvt, Vt);
    attn_mfma<<<dim3(SEQ / 64, BATCH * HEADS), 256, 0, stream>>>(Qh, Ql, Kh, Kl,
                                                                 Vt, Cb);
    oproj_mfma<<<dim3(32, 8), 256, 0, stream>>>(Cb, Woh, x, Y);
}

// Round 7
// 266.426 us; speedup vs baseline: 4.0860x; 1.0776x over previous
//
#include <hip/hip_runtime.h>

#define EMB   1024
#define HEADS 16
#define HDIM  64
#define BATCH 2
#define SEQ   2048
#define MROWS (BATCH*SEQ)   // 4096
#define STR   40            // qkv/oproj LDS k-stride in u16: 80 B
#define QSCALE 0.1803368801111204f   // 0.125 * log2(e): Q pre-scale -> exp2 softmax

typedef __attribute__((ext_vector_type(8))) short bf16x8;   // 8 bf16 (4 VGPRs)
typedef __attribute__((ext_vector_type(4))) float f32x4;    // MFMA C/D
typedef unsigned short u16;

__device__ __forceinline__ u16 f2bf(float f) {              // round-to-nearest-even
    unsigned u = __float_as_uint(f);
    u += 0x7fffu + ((u >> 16) & 1u);
    return (u16)(u >> 16);
}
__device__ __forceinline__ float bf2f(u16 h) {
    return __uint_as_float((unsigned)h << 16);
}
__device__ __forceinline__ float fast_exp2(float x) {
#if __has_builtin(__builtin_amdgcn_exp2f)
    return __builtin_amdgcn_exp2f(x);
#else
    return __expf(x * 0.6931471805599453f);
#endif
}
// pack two floats -> two truncated bf16 in one v_perm_b32 (lo in [15:0])
__device__ __forceinline__ unsigned pk_trunc(float lo, float hi) {
    return __builtin_amdgcn_perm(__float_as_uint(hi), __float_as_uint(lo),
                                 0x07060302u);
}

// XOR-swizzled LDS offset (u16 units): 64-u16 rows, 8-u16 chunks, chunk^=row&7.
#define SWZ(r, ch) ((((r) << 6)) + ((((ch) ^ ((r) & 7))) << 3))

// ---------------------------------------------------------------------------
// prep1: fused  [bx<2048] X->Xh/Xl split  |  [else] Wq/Wk transpose+hi/lo.
// ---------------------------------------------------------------------------
__global__ __launch_bounds__(256)
void prep1(const float* __restrict__ X, const float* __restrict__ Wq,
           const float* __restrict__ Wk,
           u16* __restrict__ Xh, u16* __restrict__ Xl,
           u16* __restrict__ Qth, u16* __restrict__ Qtl,
           u16* __restrict__ Kth, u16* __restrict__ Ktl)
{
    const int bx = blockIdx.x;
    if (bx < 2048) {                       // xsplit: 8 elems/thread
        int i = (bx * 256 + threadIdx.x) * 8;
#pragma unroll
        for (int half = 0; half < 2; ++half) {
            float4 v = *(const float4*)(X + i + half * 4);
            ushort4 hi, lo;
            hi.x = f2bf(v.x); lo.x = f2bf(v.x - bf2f(hi.x));
            hi.y = f2bf(v.y); lo.y = f2bf(v.y - bf2f(hi.y));
            hi.z = f2bf(v.z); lo.z = f2bf(v.z - bf2f(hi.z));
            hi.w = f2bf(v.w); lo.w = f2bf(v.w - bf2f(hi.w));
            *(ushort4*)(Xh + i + half * 4) = hi;
            *(ushort4*)(Xl + i + half * 4) = lo;
        }
    } else {                               // wtrans: [16][1024][64] -> [h*64+d][e]
        const int f = bx - 2048;           // 0..1023
        const int z = f >> 9, y = (f >> 5) & 15, x = f & 31;
        const float* W  = z ? Wk  : Wq;
        u16* Oh         = z ? Kth : Qth;
        u16* Ol         = z ? Ktl : Qtl;
        const int d  = threadIdx.x & 63;
        const int e0 = (x * 4 + (threadIdx.x >> 6)) * 8;
        const float* src = W + ((size_t)y * EMB + e0) * HDIM + d;
        ushort4 h0, h1, l0, l1;
        float v; u16 hv;
        v = src[0 * 64]; hv = f2bf(v); h0.x = hv; l0.x = f2bf(v - bf2f(hv));
        v = src[1 * 64]; hv = f2bf(v); h0.y = hv; l0.y = f2bf(v - bf2f(hv));
        v = src[2 * 64]; hv = f2bf(v); h0.z = hv; l0.z = f2bf(v - bf2f(hv));
        v = src[3 * 64]; hv = f2bf(v); h0.w = hv; l0.w = f2bf(v - bf2f(hv));
        v = src[4 * 64]; hv = f2bf(v); h1.x = hv; l1.x = f2bf(v - bf2f(hv));
        v = src[5 * 64]; hv = f2bf(v); h1.y = hv; l1.y = f2bf(v - bf2f(hv));
        v = src[6 * 64]; hv = f2bf(v); h1.z = hv; l1.z = f2bf(v - bf2f(hv));
        v = src[7 * 64]; hv = f2bf(v); h1.w = hv; l1.w = f2bf(v - bf2f(hv));
        size_t obase = ((size_t)y * HDIM + d) * EMB + e0;
        *(ushort4*)(Oh + obase)     = h0;
        *(ushort4*)(Oh + obase + 4) = h1;
        *(ushort4*)(Ol + obase)     = l0;
        *(ushort4*)(Ol + obase + 4) = l1;
    }
}

// ---------------------------------------------------------------------------
// prep2 (after qkv_z01): [f<512] Wv transpose->bf16  |  [else] Wo -> bf16.
// ---------------------------------------------------------------------------
__global__ __launch_bounds__(256)
void prep2(const float* __restrict__ Wv, const float* __restrict__ Wo,
           u16* __restrict__ Vth, u16* __restrict__ Woh)
{
    const int f = blockIdx.x;
    if (f < 512) {
        const int y = f >> 5, x = f & 31;
        const int d  = threadIdx.x & 63;
        const int e0 = (x * 4 + (threadIdx.x >> 6)) * 8;
        const float* src = Wv + ((size_t)y * EMB + e0) * HDIM + d;
        ushort4 h0, h1;
        h0.x = f2bf(src[0 * 64]); h0.y = f2bf(src[1 * 64]);
        h0.z = f2bf(src[2 * 64]); h0.w = f2bf(src[3 * 64]);
        h1.x = f2bf(src[4 * 64]); h1.y = f2bf(src[5 * 64]);
        h1.z = f2bf(src[6 * 64]); h1.w = f2bf(src[7 * 64]);
        size_t obase = ((size_t)y * HDIM + d) * EMB + e0;
        *(ushort4*)(Vth + obase)     = h0;
        *(ushort4*)(Vth + obase + 4) = h1;
    } else {
        int i = ((f - 512) * 256 + threadIdx.x) * 8;
#pragma unroll
        for (int half = 0; half < 2; ++half) {
            float4 v = *(const float4*)(Wo + i + half * 4);
            ushort4 o;
            o.x = f2bf(v.x); o.y = f2bf(v.y); o.z = f2bf(v.z); o.w = f2bf(v.w);
            *(ushort4*)(Woh + i + half * 4) = o;
        }
    }
}

// ---------------------------------------------------------------------------
// Kernel 1a: Q/K projection, 3-pass split-bf16, 2-DEEP pipelined prefetch
// (grid gives 2 blocks/CU; 1-iter window < HBM latency -> go 2 iters).
// ---------------------------------------------------------------------------
__global__ __launch_bounds__(256, 2)
void qkv_z01(const u16* __restrict__ Xh, const u16* __restrict__ Xl,
             const u16* __restrict__ Wqh, const u16* __restrict__ Wql,
             const u16* __restrict__ Wkh, const u16* __restrict__ Wkl,
             u16* __restrict__ Qh, u16* __restrict__ Ql,
             u16* __restrict__ Kh, u16* __restrict__ Kl)
{
    const int z  = blockIdx.z;
    const int m0 = blockIdx.x * 128;
    const int n0 = blockIdx.y * 128;
    const int t    = threadIdx.x;
    const int wave = t >> 6, lane = t & 63;
    const int wm = wave & 1, wn = wave >> 1;
    const int l16 = lane & 15, quad = lane >> 4;

    __shared__ u16 Ahs[128][STR];
    __shared__ u16 Als[128][STR];
    __shared__ u16 Bhs[128][STR];
    __shared__ u16 Bls[128][STR];

    const u16* Bh_g = z ? Wkh : Wqh;
    const u16* Bl_g = z ? Wkl : Wql;

    const int ar0 = t >> 2, ak = (t & 3) * 8, ar1 = ar0 + 64;

    f32x4 acc[4][4];
#pragma unroll
    for (int i = 0; i < 4; ++i)
#pragma unroll
        for (int j = 0; j < 4; ++j) acc[i][j] = (f32x4){0.f, 0.f, 0.f, 0.f};

    bf16x8 cur[8], nxt[8], nx2[8];
#define QK_LOAD(dst, kk)                                                        \
    do {                                                                        \
        dst[0] = *(const bf16x8*)(Xh  + (size_t)(m0 + ar0) * EMB + (kk) + ak);  \
        dst[1] = *(const bf16x8*)(Xh  + (size_t)(m0 + ar1) * EMB + (kk) + ak);  \
        dst[2] = *(const bf16x8*)(Xl  + (size_t)(m0 + ar0) * EMB + (kk) + ak);  \
        dst[3] = *(const bf16x8*)(Xl  + (size_t)(m0 + ar1) * EMB + (kk) + ak);  \
        dst[4] = *(const bf16x8*)(Bh_g + (size_t)(n0 + ar0) * EMB + (kk) + ak); \
        dst[5] = *(const bf16x8*)(Bh_g + (size_t)(n0 + ar1) * EMB + (kk) + ak); \
        dst[6] = *(const bf16x8*)(Bl_g + (size_t)(n0 + ar0) * EMB + (kk) + ak); \
        dst[7] = *(const bf16x8*)(Bl_g + (size_t)(n0 + ar1) * EMB + (kk) + ak); \
    } while (0)

    QK_LOAD(cur, 0);
    QK_LOAD(nxt, 32);

    for (int k0 = 0; k0 < EMB; k0 += 32) {
        __syncthreads();
        *(bf16x8*)&Ahs[ar0][ak] = cur[0];  *(bf16x8*)&Ahs[ar1][ak] = cur[1];
        *(bf16x8*)&Als[ar0][ak] = cur[2];  *(bf16x8*)&Als[ar1][ak] = cur[3];
        *(bf16x8*)&Bhs[ar0][ak] = cur[4];  *(bf16x8*)&Bhs[ar1][ak] = cur[5];
        *(bf16x8*)&Bls[ar0][ak] = cur[6];  *(bf16x8*)&Bls[ar1][ak] = cur[7];
        __syncthreads();

        const int kn = (k0 + 64 < EMB) ? k0 + 64 : 0;   // dummy reload at end
        QK_LOAD(nx2, kn);

        bf16x8 B4h[4], B4l[4];
#pragma unroll
        for (int j = 0; j < 4; ++j) {
            B4h[j] = *(const bf16x8*)&Bhs[wn * 64 + 16 * j + l16][quad * 8];
            B4l[j] = *(const bf16x8*)&Bls[wn * 64 + 16 * j + l16][quad * 8];
        }
#pragma unroll
        for (int i = 0; i < 4; ++i) {
            bf16x8 Ai_h = *(const bf16x8*)&Ahs[wm * 64 + 16 * i + l16][quad * 8];
            bf16x8 Ai_l = *(const bf16x8*)&Als[wm * 64 + 16 * i + l16][quad * 8];
#pragma unroll
            for (int j = 0; j < 4; ++j) {
                acc[i][j] = __builtin_amdgcn_mfma_f32_16x16x32_bf16(Ai_h, B4h[j], acc[i][j], 0, 0, 0);
                acc[i][j] = __builtin_amdgcn_mfma_f32_16x16x32_bf16(Ai_h, B4l[j], acc[i][j], 0, 0, 0);
                acc[i][j] = __builtin_amdgcn_mfma_f32_16x16x32_bf16(Ai_l, B4h[j], acc[i][j], 0, 0, 0);
            }
        }
#pragma unroll
        for (int q = 0; q < 8; ++q) { cur[q] = nxt[q]; nxt[q] = nx2[q]; }
    }
#undef QK_LOAD

    const int b = m0 >> 11;
    const int h = (n0 + wn * 64) >> 6;
    u16* Oh = z ? Kh : Qh;
    u16* Ol = z ? Kl : Ql;
    const float esc = z ? 1.0f : QSCALE;    // Q carries the softmax scale
#pragma unroll
    for (int i = 0; i < 4; ++i)
#pragma unroll
        for (int r = 0; r < 4; ++r) {
            int tt = (m0 & (SEQ - 1)) + wm * 64 + 16 * i + quad * 4 + r;
            size_t rowbase = ((size_t)(b * HEADS + h) * SEQ + tt) * HDIM;
#pragma unroll
            for (int j = 0; j < 4; ++j) {
                int d = 16 * j + l16;
                float v = acc[i][j][r] * esc;
                u16 hv = f2bf(v);
                Oh[rowbase + d] = hv;
                Ol[rowbase + d] = f2bf(v - bf2f(hv));
            }
        }
}

// ---------------------------------------------------------------------------
// Kernel 1b: V projection, 1-pass bf16, 2-deep pipelined.  Writes Vt[bh][d][t].
// ---------------------------------------------------------------------------
__global__ __launch_bounds__(256, 2)
void qkv_v(const u16* __restrict__ Xh, const u16* __restrict__ Wvt,
           u16* __restrict__ Vt)
{
    const int m0 = blockIdx.x * 128;
    const int n0 = blockIdx.y * 128;
    const int t    = threadIdx.x;
    const int wave = t >> 6, lane = t & 63;
    const int wm = wave & 1, wn = wave >> 1;
    const int l16 = lane & 15, quad = lane >> 4;

    __shared__ u16 Ahs[128][STR];
    __shared__ u16 Bhs[128][STR];

    const int ar0 = t >> 2, ak = (t & 3) * 8, ar1 = ar0 + 64;

    f32x4 acc[4][4];
#pragma unroll
    for (int i = 0; i < 4; ++i)
#pragma unroll
        for (int j = 0; j < 4; ++j) acc[i][j] = (f32x4){0.f, 0.f, 0.f, 0.f};

    bf16x8 cur[4], nxt[4], nx2[4];
#define V_LOAD(dst, kk)                                                         \
    do {                                                                        \
        dst[0] = *(const bf16x8*)(Xh  + (size_t)(m0 + ar0) * EMB + (kk) + ak);  \
        dst[1] = *(const bf16x8*)(Xh  + (size_t)(m0 + ar1) * EMB + (kk) + ak);  \
        dst[2] = *(const bf16x8*)(Wvt + (size_t)(n0 + ar0) * EMB + (kk) + ak);  \
        dst[3] = *(const bf16x8*)(Wvt + (size_t)(n0 + ar1) * EMB + (kk) + ak);  \
    } while (0)

    V_LOAD(cur, 0);
    V_LOAD(nxt, 32);

    for (int k0 = 0; k0 < EMB; k0 += 32) {
        __syncthreads();
        *(bf16x8*)&Ahs[ar0][ak] = cur[0];  *(bf16x8*)&Ahs[ar1][ak] = cur[1];
        *(bf16x8*)&Bhs[ar0][ak] = cur[2];  *(bf16x8*)&Bhs[ar1][ak] = cur[3];
        __syncthreads();

        const int kn = (k0 + 64 < EMB) ? k0 + 64 : 0;
        V_LOAD(nx2, kn);

        bf16x8 B4[4];
#pragma unroll
        for (int j = 0; j < 4; ++j)
            B4[j] = *(const bf16x8*)&Bhs[wn * 64 + 16 * j + l16][quad * 8];
#pragma unroll
        for (int i = 0; i < 4; ++i) {
            bf16x8 Ai = *(const bf16x8*)&Ahs[wm * 64 + 16 * i + l16][quad * 8];
#pragma unroll
            for (int j = 0; j < 4; ++j)
                acc[i][j] = __builtin_amdgcn_mfma_f32_16x16x32_bf16(Ai, B4[j], acc[i][j], 0, 0, 0);
        }
#pragma unroll
        for (int q = 0; q < 4; ++q) { cur[q] = nxt[q]; nxt[q] = nx2[q]; }
    }
#undef V_LOAD

    const int b = m0 >> 11;
    const int h = (n0 + wn * 64) >> 6;
#pragma unroll
    for (int i = 0; i < 4; ++i)
#pragma unroll
        for (int j = 0; j < 4; ++j) {
            int d  = 16 * j + l16;
            int tt = (m0 & (SEQ - 1)) + wm * 64 + 16 * i + quad * 4;
            ushort4 o;
            o.x = f2bf(acc[i][j][0]); o.y = f2bf(acc[i][j][1]);
            o.z = f2bf(acc[i][j][2]); o.w = f2bf(acc[i][j][3]);
            *(ushort4*)(Vt + ((size_t)(b * HEADS + h) * HDIM + d) * SEQ + tt) = o;
        }
}

// ---------------------------------------------------------------------------
// Kernel 2: flash attention, transposed-score MFMA, 128-q block (32 q/wave):
// K/V LDS reads amortize over 2x MFMA -> halves LDS bytes/FLOP (the R6
// bottleneck).  XOR-swizzled LDS, log2 softmax, v_perm P-pack retained.
// grid (SEQ/128, BATCH*HEADS) = (16, 32).
// ---------------------------------------------------------------------------
__global__ __launch_bounds__(256, 2)
void attn_mfma(const u16* __restrict__ Qh, const u16* __restrict__ Ql,
               const u16* __restrict__ Kh, const u16* __restrict__ Kl,
               const u16* __restrict__ Vt, u16* __restrict__ Cb)
{
    const int qt0  = blockIdx.x * 128;
    const int bh   = blockIdx.y;
    const int t    = threadIdx.x;
    const int wave = t >> 6;
    const int lane = t & 63;
    const int l16  = lane & 15;
    const int quad = lane >> 4;

    __shared__ u16 Ksh[4096];   // K hi [s][d], swizzled
    __shared__ u16 Ksl[4096];   // K lo [s][d], swizzled
    __shared__ u16 Vs [4096];   // V^T  [d][s], swizzled
    __shared__ u16 Ps [8192];   // P    [q:128][s:64], swizzled

    const size_t bh_off = (size_t)bh * SEQ * HDIM;
    const u16* Qhb = Qh + bh_off;
    const u16* Qlb = Ql + bh_off;
    const u16* Khb = Kh + bh_off;
    const u16* Klb = Kl + bh_off;
    const u16* Vtb = Vt + bh_off;   // [64][SEQ]

    // Q fragments, 2 groups of 16 q-rows each (g*64 apart)
    bf16x8 aQh[2][2], aQl[2][2];
#pragma unroll
    for (int g = 0; g < 2; ++g) {
        const int qrow = qt0 + g * 64 + wave * 16 + l16;
        const u16* bH = Qhb + (size_t)qrow * HDIM + quad * 8;
        const u16* bL = Qlb + (size_t)qrow * HDIM + quad * 8;
        aQh[g][0] = *(const bf16x8*)(bH);
        aQh[g][1] = *(const bf16x8*)(bH + 32);
        aQl[g][0] = *(const bf16x8*)(bL);
        aQl[g][1] = *(const bf16x8*)(bL + 32);
    }

    f32x4 accO[2][4];
    float m_i[2] = {-1e30f, -1e30f}, l_i[2] = {0.f, 0.f};
#pragma unroll
    for (int g = 0; g < 2; ++g)
#pragma unroll
        for (int j = 0; j < 4; ++j) accO[g][j] = (f32x4){0.f, 0.f, 0.f, 0.f};

    const int sr0 = t >> 3, sch = t & 7, sr1 = sr0 + 32;
    const int gc  = sch * 8;
    const int so0 = SWZ(sr0, sch), so1 = SWZ(sr1, sch);

    bf16x8 cur[6], nxt[6];
#define KV_LOAD(dst, ss)                                                       \
    do {                                                                       \
        dst[0] = *(const bf16x8*)(Khb + (size_t)((ss) + sr0) * HDIM + gc);     \
        dst[1] = *(const bf16x8*)(Khb + (size_t)((ss) + sr1) * HDIM + gc);     \
        dst[2] = *(const bf16x8*)(Klb + (size_t)((ss) + sr0) * HDIM + gc);     \
        dst[3] = *(const bf16x8*)(Klb + (size_t)((ss) + sr1) * HDIM + gc);     \
        dst[4] = *(const bf16x8*)(Vtb + (size_t)sr0 * SEQ + (ss) + gc);        \
        dst[5] = *(const bf16x8*)(Vtb + (size_t)sr1 * SEQ + (ss) + gc);        \
    } while (0)

    KV_LOAD(cur, 0);

    for (int s0 = 0; s0 < SEQ; s0 += 64) {
        __syncthreads();
        *(bf16x8*)&Ksh[so0] = cur[0];  *(bf16x8*)&Ksh[so1] = cur[1];
        *(bf16x8*)&Ksl[so0] = cur[2];  *(bf16x8*)&Ksl[so1] = cur[3];
        *(bf16x8*)&Vs [so0] = cur[4];  *(bf16x8*)&Vs [so1] = cur[5];
        __syncthreads();

        const int sn = (s0 + 64 < SEQ) ? s0 + 64 : 0;
        KV_LOAD(nxt, sn);

        // ---- S^T = K Q^T (3-pass split), both q-groups share K reads ----
        f32x4 accS[2][4];
#pragma unroll
        for (int g = 0; g < 2; ++g)
#pragma unroll
            for (int i = 0; i < 4; ++i) accS[g][i] = (f32x4){0.f, 0.f, 0.f, 0.f};
#pragma unroll
        for (int c = 0; c < 2; ++c) {
#pragma unroll
            for (int i = 0; i < 4; ++i) {
                bf16x8 kh_ = *(const bf16x8*)&Ksh[SWZ(16 * i + l16, 4 * c + quad)];
                bf16x8 kl_ = *(const bf16x8*)&Ksl[SWZ(16 * i + l16, 4 * c + quad)];
                accS[0][i] = __builtin_amdgcn_mfma_f32_16x16x32_bf16(kh_, aQh[0][c], accS[0][i], 0, 0, 0);
                accS[0][i] = __builtin_amdgcn_mfma_f32_16x16x32_bf16(kl_, aQh[0][c], accS[0][i], 0, 0, 0);
                accS[0][i] = __builtin_amdgcn_mfma_f32_16x16x32_bf16(kh_, aQl[0][c], accS[0][i], 0, 0, 0);
                accS[1][i] = __builtin_amdgcn_mfma_f32_16x16x32_bf16(kh_, aQh[1][c], accS[1][i], 0, 0, 0);
                accS[1][i] = __builtin_amdgcn_mfma_f32_16x16x32_bf16(kl_, aQh[1][c], accS[1][i], 0, 0, 0);
                accS[1][i] = __builtin_amdgcn_mfma_f32_16x16x32_bf16(kh_, aQl[1][c], accS[1][i], 0, 0, 0);
            }
        }

        // ---- online softmax per group (lane owns q-row; 2 shfl each) ----
#pragma unroll
        for (int g = 0; g < 2; ++g) {
            float vmax = fmaxf(fmaxf(accS[g][0][0], accS[g][0][1]),
                               fmaxf(accS[g][0][2], accS[g][0][3]));
#pragma unroll
            for (int i = 1; i < 4; ++i)
                vmax = fmaxf(vmax, fmaxf(fmaxf(accS[g][i][0], accS[g][i][1]),
                                         fmaxf(accS[g][i][2], accS[g][i][3])));
            vmax = fmaxf(vmax, __shfl_xor(vmax, 16, 64));
            vmax = fmaxf(vmax, __shfl_xor(vmax, 32, 64));
            float mn   = fmaxf(m_i[g], vmax);
            float alph = fast_exp2(m_i[g] - mn);
            m_i[g] = mn;
            float P[4][4], s = 0.f;
#pragma unroll
            for (int i = 0; i < 4; ++i)
#pragma unroll
                for (int r = 0; r < 4; ++r) {
                    P[i][r] = fast_exp2(accS[g][i][r] - mn);
                    s += P[i][r];
                }
            s += __shfl_xor(s, 16, 64);
            s += __shfl_xor(s, 32, 64);
            l_i[g] = l_i[g] * alph + s;
#pragma unroll
            for (int j = 0; j < 4; ++j) accO[g][j] *= alph;

            const int prow = g * 64 + wave * 16 + l16;
#pragma unroll
            for (int i = 0; i < 4; ++i) {
                uint2 pv;
                pv.x = pk_trunc(P[i][0], P[i][1]);
                pv.y = pk_trunc(P[i][2], P[i][3]);
                *(uint2*)&Ps[SWZ(prow, 2 * i + (quad >> 1)) + ((quad & 1) << 2)] = pv;
            }
        }

        // ---- O^T += V^T P^T  (V reads shared across both q-groups) ----
#pragma unroll
        for (int c = 0; c < 2; ++c) {
            bf16x8 bP0 = *(const bf16x8*)&Ps[SWZ(wave * 16 + l16,      4 * c + quad)];
            bf16x8 bP1 = *(const bf16x8*)&Ps[SWZ(64 + wave * 16 + l16, 4 * c + quad)];
#pragma unroll
            for (int j = 0; j < 4; ++j) {
                bf16x8 aV = *(const bf16x8*)&Vs[SWZ(16 * j + l16, 4 * c + quad)];
                accO[0][j] = __builtin_amdgcn_mfma_f32_16x16x32_bf16(aV, bP0, accO[0][j], 0, 0, 0);
                accO[1][j] = __builtin_amdgcn_mfma_f32_16x16x32_bf16(aV, bP1, accO[1][j], 0, 0, 0);
            }
        }
#pragma unroll
        for (int q = 0; q < 6; ++q) cur[q] = nxt[q];
    }
#undef KV_LOAD

    const int b = bh >> 4, h = bh & 15;
#pragma unroll
    for (int g = 0; g < 2; ++g) {
        const int row = qt0 + g * 64 + wave * 16 + l16;
        const float inv = 1.f / l_i[g];
#pragma unroll
        for (int j = 0; j < 4; ++j) {
            ushort4 o;
            o.x = f2bf(accO[g][j][0] * inv); o.y = f2bf(accO[g][j][1] * inv);
            o.z = f2bf(accO[g][j][2] * inv); o.w = f2bf(accO[g][j][3] * inv);
            *(ushort4*)&Cb[((size_t)b * SEQ + row) * EMB + h * HDIM + 16 * j + quad * 4] = o;
        }
    }
}

// ---------------------------------------------------------------------------
// Kernel 3: Y = X + C @ Wo^T, bf16 MFMA, 128x128, 2-deep pipelined.
// ---------------------------------------------------------------------------
__global__ __launch_bounds__(256, 2)
void oproj_mfma(const u16* __restrict__ Cb, const u16* __restrict__ Woh,
                const float* __restrict__ X, float* __restrict__ Y)
{
    const int m0 = blockIdx.x * 128;
    const int n0 = blockIdx.y * 128;
    const int t    = threadIdx.x;
    const int wave = t >> 6, lane = t & 63;
    const int wm = wave & 1, wn = wave >> 1;
    const int l16 = lane & 15, quad = lane >> 4;

    __shared__ u16 Ahs[128][STR];
    __shared__ u16 Bhs[128][STR];

    const int ar0 = t >> 2, ak = (t & 3) * 8, ar1 = ar0 + 64;

    f32x4 acc[4][4];
#pragma unroll
    for (int i = 0; i < 4; ++i)
#pragma unroll
        for (int j = 0; j < 4; ++j) acc[i][j] = (f32x4){0.f, 0.f, 0.f, 0.f};

    bf16x8 cur[4], nxt[4], nx2[4];
#define O_LOAD(dst, kk)                                                         \
    do {                                                                        \
        dst[0] = *(const bf16x8*)(Cb  + (size_t)(m0 + ar0) * EMB + (kk) + ak);  \
        dst[1] = *(const bf16x8*)(Cb  + (size_t)(m0 + ar1) * EMB + (kk) + ak);  \
        dst[2] = *(const bf16x8*)(Woh + (size_t)(n0 + ar0) * EMB + (kk) + ak);  \
        dst[3] = *(const bf16x8*)(Woh + (size_t)(n0 + ar1) * EMB + (kk) + ak);  \
    } while (0)

    O_LOAD(cur, 0);
    O_LOAD(nxt, 32);

    for (int k0 = 0; k0 < EMB; k0 += 32) {
        __syncthreads();
        *(bf16x8*)&Ahs[ar0][ak] = cur[0];  *(bf16x8*)&Ahs[ar1][ak] = cur[1];
        *(bf16x8*)&Bhs[ar0][ak] = cur[2];  *(bf16x8*)&Bhs[ar1][ak] = cur[3];
        __syncthreads();

        const int kn = (k0 + 64 < EMB) ? k0 + 64 : 0;
        O_LOAD(nx2, kn);

        bf16x8 B4[4];
#pragma unroll
        for (int j = 0; j < 4; ++j)
            B4[j] = *(const bf16x8*)&Bhs[wn * 64 + 16 * j + l16][quad * 8];
#pragma unroll
        for (int i = 0; i < 4; ++i) {
            bf16x8 Ai = *(const bf16x8*)&Ahs[wm * 64 + 16 * i + l16][quad * 8];
#pragma unroll
            for (int j = 0; j < 4; ++j)
                acc[i][j] = __builtin_amdgcn_mfma_f32_16x16x32_bf16(Ai, B4[j], acc[i][j], 0, 0, 0);
        }
#pragma unroll
        for (int q = 0; q < 4; ++q) { cur[q] = nxt[q]; nxt[q] = nx2[q]; }
    }
#undef O_LOAD

#pragma unroll
    for (int i = 0; i < 4; ++i)
#pragma unroll
        for (int r = 0; r < 4; ++r) {
            int m = m0 + wm * 64 + 16 * i + quad * 4 + r;
#pragma unroll
            for (int j = 0; j < 4; ++j) {
                int n = n0 + wn * 64 + 16 * j + l16;
                Y[(size_t)m * EMB + n] = acc[i][j][r] + X[(size_t)m * EMB + n];
            }
        }
}

// ---------------------------------------------------------------------------
// Workspace map (u16 units, 32M total = 64 MiB):
//   [0]   Qh 4M   [4M] Ql   [8M] Kh   [12M] Kl   [16M] Vt
//   [20M] Xh 4M   (-> Cb after qkv_v)
//   [24M] Xl 4M   (-> Woh after qkv_z01, written by prep2)
//   [28M] Wtq_h 1M (-> Wvt after qkv_z01, written by prep2), Wtq_l, Wtk_h, Wtk_l
// ---------------------------------------------------------------------------
extern "C" void kernel_launch(void* const* d_in, const int* in_sizes, int n_in,
                              void* d_out, int out_size, void* d_ws,
                              size_t ws_size, hipStream_t stream)
{
    const float* x  = (const float*)d_in[0];
    const float* Wq = (const float*)d_in[1];
    const float* Wk = (const float*)d_in[2];
    const float* Wv = (const float*)d_in[3];
    const float* Wo = (const float*)d_in[4];
    float* Y = (float*)d_out;

    const size_t NPER = (size_t)MROWS * EMB;   // 4,194,304
    u16* base  = (u16*)d_ws;
    u16* Qh    = base;
    u16* Ql    = Qh + NPER;
    u16* Kh    = Ql + NPER;
    u16* Kl    = Kh + NPER;
    u16* Vt    = Kl + NPER;
    u16* Xh    = Vt + NPER;
    u16* Xl    = Xh + NPER;
    u16* Wtq_h = Xl + NPER;
    u16* Wtq_l = Wtq_h + EMB * EMB;
    u16* Wtk_h = Wtq_l + EMB * EMB;
    u16* Wtk_l = Wtk_h + EMB * EMB;
    u16* Wvt   = Wtq_h;   // alias: Wtq dead after qkv_z01
    u16* Cb    = Xh;      // alias: Xh dead after qkv_v
    u16* Woh   = Xl;      // alias: Xl dead after qkv_z01

    prep1<<<dim3(3072), 256, 0, stream>>>(x, Wq, Wk, Xh, Xl,
                                          Wtq_h, Wtq_l, Wtk_h, Wtk_l);
    qkv_z01<<<dim3(32, 8, 2), 256, 0, stream>>>(Xh, Xl, Wtq_h, Wtq_l,
                                                Wtk_h, Wtk_l, Qh, Ql, Kh, Kl);
    prep2<<<dim3(1024), 256, 0, stream>>>(Wv, Wo, Wvt, Woh);
    qkv_v<<<dim3(32, 8), 256, 0, stream>>>(Xh, Wvt, Vt);
    attn_mfma<<<dim3(SEQ / 128, BATCH * HEADS), 256, 0, stream>>>(Qh, Ql, Kh, Kl,
                                                                  Vt, Cb);
    oproj_mfma<<<dim3(32, 8), 256, 0, stream>>>(Cb, Woh, x, Y);
}